// Round 3
// baseline (310.016 us; speedup 1.0000x reference)
//
#include <hip/hip_runtime.h>

typedef unsigned short u16;
typedef unsigned int u32;
typedef short bf16x8 __attribute__((ext_vector_type(8)));
typedef float f32x4 __attribute__((ext_vector_type(4)));

#define B_ 2
#define L_ 2048
#define H_ 16
#define KV_ 4
#define D_ 128
#define HID_ 2048

// 1/sqrt(128) * log2(e): folded into Q so softmax runs in exp2 domain.
#define QSCALE (0.08838834764831845f * 1.4426950408889634f)

__device__ __forceinline__ u16 f2bf(float f) {
  union { float f; u32 u; } v; v.f = f;
  u32 u = v.u;
  return (u16)((u + 0x7FFFu + ((u >> 16) & 1u)) >> 16);
}
__device__ __forceinline__ float bf2f(u16 h) {
  union { u32 u; float f; } v; v.u = ((u32)h) << 16;
  return v.f;
}
__device__ __forceinline__ u32 pkbf(float a, float b) {
  union { float f; u32 u; } x, y; x.f = a; y.f = b;
  return ((x.u + 0x8000u) >> 16) | ((y.u + 0x8000u) & 0xffff0000u);
}
__device__ __forceinline__ void gl_lds16(const void* g, void* l) {
  __builtin_amdgcn_global_load_lds((__attribute__((address_space(1))) void*)(g),
                                   (__attribute__((address_space(3))) void*)(l),
                                   16, 0, 0);
}

template <int N> __device__ __forceinline__ void vmwait() {
  asm volatile("s_waitcnt vmcnt(%0)" ::"n"(N) : "memory");
}
#define LGKM0() asm volatile("s_waitcnt lgkmcnt(0)" ::: "memory")
#define BARRIER()                                                         \
  do {                                                                    \
    asm volatile("" ::: "memory");                                        \
    __builtin_amdgcn_s_barrier();                                         \
    asm volatile("" ::: "memory");                                        \
  } while (0)

// ---------------- prep: fp32->bf16 X convert + all weight transposes ----------------
__global__ void k_prep(const float* __restrict__ hidden, u16* __restrict__ Xb,
                       const float* __restrict__ Wq, const float* __restrict__ Wk,
                       const float* __restrict__ Wv, const float* __restrict__ Wo,
                       u16* __restrict__ Wtqkv, u16* __restrict__ Wto) {
  __shared__ float t[32][33];
  int id = blockIdx.x;
  if (id < 8192) {
    int i = id * 256 + threadIdx.x;
    float4 v = ((const float4*)hidden)[i];
    u32 a = (u32)f2bf(v.x) | ((u32)f2bf(v.y) << 16);
    u32 b = (u32)f2bf(v.z) | ((u32)f2bf(v.w) << 16);
    ((uint2*)Xb)[i] = make_uint2(a, b);
    return;
  }
  id -= 8192;
  const float* src; u16* dst; int C; int ct, rt;
  if (id < 4096)      { src = Wq; dst = Wtqkv;               C = 2048; ct = id & 63; rt = id >> 6; }
  else if (id < 5120) { id -= 4096; src = Wk; dst = Wtqkv + 2048 * 2048; C = 512; ct = id & 15; rt = id >> 4; }
  else if (id < 6144) { id -= 5120; src = Wv; dst = Wtqkv + 2560 * 2048; C = 512; ct = id & 15; rt = id >> 4; }
  else                { id -= 6144; src = Wo; dst = Wto;     C = 2048; ct = id & 63; rt = id >> 6; }
  const int R = 2048;
  int c0 = ct * 32, r0 = rt * 32;
  int tx = threadIdx.x & 31, ty = threadIdx.x >> 5;
  for (int i = ty; i < 32; i += 8)
    t[i][tx] = src[(size_t)(r0 + i) * C + c0 + tx];
  __syncthreads();
  for (int i = ty; i < 32; i += 8)
    dst[(size_t)(c0 + i) * R + r0 + tx] = f2bf(t[tx][i]);
}

// ---------------- fused QKV GEMM (256^2, m201 8-phase) + RMSnorm + RoPE + V-trans ------
// C(4096x3072) = Xb @ Wtqkv^T. BM=BN=256, BK=64, 8 waves (2Mx4N), 128KB LDS dbuf.
// m201 phase shape: {ds_read frags; issue stage; barrier; lgkmcnt(0); setprio(1);
// 16 MFMA; setprio(0); [counted vmwait]; barrier}. ds_reads complete during the
// barrier wait; MFMAs start with lgkm drained. Counted vmcnt(4) at P0/P1/P3 ends
// (never 0 in loop). Safety invariant: region R's ds_reads issue only after a
// barrier preceded (in every wave) by a vmcnt draining that wave's writes to R.
// Ledger (issue order A0,B0,B1,A1 per tile): P3end vm4 -> A0,B0 done for next P0;
// P0end vm4 -> B1 done for P1; P1end vm4 -> A1 done for P2.
__global__ __launch_bounds__(512, 2) void k_gemm_qkv(
    const u16* __restrict__ A, const u16* __restrict__ Bt,
    const float* __restrict__ cosp, const float* __restrict__ sinp,
    const float* __restrict__ qw, const float* __restrict__ kw,
    u16* __restrict__ Qb, u16* __restrict__ Kb, u16* __restrict__ Vtb) {
  extern __shared__ char smem[];  // 131072B: A dbuf 2x32KB | B dbuf 2x32KB
  const int tid = threadIdx.x;
  const int wave = tid >> 6, lane = tid & 63;
  const int wm = wave >> 2, wn = wave & 3;
  const int quad = lane >> 4, fm = lane & 15;
  const int f7 = fm & 7;

  // bijective XCD swizzle: 192 blocks, xcd = bid&7 owns 2 consecutive by rows.
  const int bid = blockIdx.x;
  const int swz = (bid & 7) * 24 + (bid >> 3);
  const int by = swz / 12, bx = swz % 12;
  const int m0 = by * 256, n0 = bx * 256;

  const u16* Ag = A + (size_t)m0 * 2048;
  const u16* Bg = Bt + (size_t)n0 * 2048;
  const int schunk = (lane & 7) ^ ((lane >> 3) & 7);  // inverse-swizzled src chunk

  f32x4 acc[8][4];
#pragma unroll
  for (int i = 0; i < 8; ++i)
#pragma unroll
    for (int j = 0; j < 4; ++j)
#pragma unroll
      for (int r = 0; r < 4; ++r) acc[i][j][r] = 0.0f;

  bf16x8 af[4][2], bf[4][2];
  const int ArowB = (wm * 128 + fm) * 128;          // byte offset of A frag row
  const int BrowB = (wn * 64 + fm) * 128;           // byte offset of B frag row
  const int kc[2] = {(quad ^ f7) * 16, ((quad ^ 4) ^ f7) * 16};  // swizzled k-chunks

#define STAGE_A(qa_, kk_, bb_)                                               \
  _Pragma("unroll") for (int q = 0; q < 2; ++q) {                            \
    int ldsoff = (bb_)*32768 + q * 16384 + (qa_)*8192 + wave * 1024 + lane * 16; \
    int grow = q * 128 + (qa_)*64 + wave * 8 + (lane >> 3);                  \
    gl_lds16(Ag + (size_t)grow * 2048 + (kk_)*64 + schunk * 8, smem + ldsoff); \
  }
#define STAGE_B(qb_, kk_, bb_)                                               \
  _Pragma("unroll") for (int q = 0; q < 2; ++q) {                            \
    int gg = q * 2 + (wave >> 2);                                            \
    int ldsoff = 65536 + (bb_)*32768 + gg * 8192 + (qb_)*4096 +              \
                 (wave & 3) * 1024 + lane * 16;                              \
    int grow = gg * 64 + (qb_)*32 + (wave & 3) * 8 + (lane >> 3);            \
    gl_lds16(Bg + (size_t)grow * 2048 + (kk_)*64 + schunk * 8, smem + ldsoff); \
  }
#define LDA4(bb_, roff_)                                                     \
  _Pragma("unroll") for (int i = 0; i < 4; ++i)                              \
    _Pragma("unroll") for (int ks = 0; ks < 2; ++ks)                         \
      af[i][ks] = *(const bf16x8*)(smem + (bb_)*32768 + ArowB + (roff_) +    \
                                   i * 2048 + kc[ks]);
#define LDB2(bb_, j0_)                                                       \
  _Pragma("unroll") for (int j = 0; j < 2; ++j)                              \
    _Pragma("unroll") for (int ks = 0; ks < 2; ++ks)                         \
      bf[(j0_) + j][ks] = *(const bf16x8*)(smem + 65536 + (bb_)*32768 +      \
                                           BrowB + ((j0_) + j) * 2048 + kc[ks]);
#define MFMA_Q(I0_, J0_)                                                     \
  __builtin_amdgcn_s_setprio(1);                                             \
  _Pragma("unroll") for (int ks = 0; ks < 2; ++ks)                           \
    _Pragma("unroll") for (int i = 0; i < 4; ++i)                            \
      _Pragma("unroll") for (int j = 0; j < 2; ++j)                          \
        acc[(I0_) + i][(J0_) + j] = __builtin_amdgcn_mfma_f32_16x16x32_bf16( \
            af[i][ks], bf[(J0_) + j][ks], acc[(I0_) + i][(J0_) + j], 0, 0, 0); \
  __builtin_amdgcn_s_setprio(0);

// steady tile: reads buf bb_, stages tile kt_+1 into bb_^1
#define TILE_ST(kt_, bb_)                                                    \
  {                                                                          \
    LDA4(bb_, 0); LDB2(bb_, 0); STAGE_A(0, (kt_) + 1, (bb_) ^ 1);            \
    BARRIER(); LGKM0(); MFMA_Q(0, 0); vmwait<4>(); BARRIER();                \
    LDB2(bb_, 2); STAGE_B(0, (kt_) + 1, (bb_) ^ 1);                          \
    BARRIER(); LGKM0(); MFMA_Q(0, 2); vmwait<4>(); BARRIER();                \
    LDA4(bb_, 8192); STAGE_B(1, (kt_) + 1, (bb_) ^ 1);                       \
    BARRIER(); LGKM0(); MFMA_Q(4, 0); BARRIER();                             \
    STAGE_A(1, (kt_) + 1, (bb_) ^ 1);                                        \
    BARRIER(); MFMA_Q(4, 2); vmwait<4>(); BARRIER();                         \
  }
// last tile: no staging; drain 2 -> 0
#define TILE_LAST(bb_)                                                       \
  {                                                                          \
    LDA4(bb_, 0); LDB2(bb_, 0);                                              \
    BARRIER(); LGKM0(); MFMA_Q(0, 0); vmwait<2>(); BARRIER();                \
    LDB2(bb_, 2);                                                            \
    BARRIER(); LGKM0(); MFMA_Q(0, 2); vmwait<0>(); BARRIER();                \
    LDA4(bb_, 8192);                                                         \
    BARRIER(); LGKM0(); MFMA_Q(4, 0); BARRIER();                             \
    MFMA_Q(4, 2);                                                            \
  }

  // prologue: tile 0 fully staged in consumption order; A0,B0 drained
  STAGE_A(0, 0, 0);
  STAGE_B(0, 0, 0);
  STAGE_B(1, 0, 0);
  STAGE_A(1, 0, 0);
  vmwait<4>();
  BARRIER();

#pragma unroll 1
  for (int t2 = 0; t2 < 30; t2 += 2) {
    TILE_ST(t2, 0);
    TILE_ST(t2 + 1, 1);
  }
  TILE_ST(30, 0);
  TILE_LAST(1);

#undef TILE_LAST
#undef TILE_ST
#undef MFMA_Q
#undef LDB2
#undef LDA4
#undef STAGE_B
#undef STAGE_A

  // ---- fused epilogue: 4 quarters, each = one head x 128 tokens ----
  u16* Cs = (u16*)smem;
  const int head2 = bx * 2;
  const int bL = by >> 3;
  const int l0 = m0 & 2047;
  __syncthreads();
#pragma unroll 1
  for (int qq = 0; qq < 4; ++qq) {
    const int qm = qq >> 1, qn = qq & 1;
    __syncthreads();
    if (wm == qm && (wn >> 1) == qn) {
#pragma unroll
      for (int i = 0; i < 8; ++i)
#pragma unroll
        for (int j = 0; j < 4; ++j)
#pragma unroll
          for (int r = 0; r < 4; ++r)
            Cs[(i * 16 + quad * 4 + r) * 136 + (wn & 1) * 64 + j * 16 + fm] =
                f2bf(acc[i][j][r]);
    }
    __syncthreads();
    const int hq = head2 + qn;
    const int tok0 = m0 + qm * 128;
    const int l0q = l0 + qm * 128;
    if (hq < 20) {
      const int isq = hq < 16;
      const float* wv = isq ? qw : kw;
      const int half = lane >> 5, sl = lane & 31;
      u16* outp = isq ? (Qb + (size_t)(bL * H_ + hq) * L_ * D_)
                      : (Kb + (size_t)(bL * KV_ + hq - 16) * L_ * D_);
      const float4 wvv = *(const float4*)(wv + sl * 4);
      for (int it = 0; it < 8; ++it) {
        int r = wave * 16 + it * 2 + half;
        const u16* crow = Cs + r * 136 + sl * 4;
        u32 c01 = *(const u32*)crow;
        u32 c23 = *(const u32*)(crow + 2);
        float x0 = bf2f((u16)(c01 & 0xffff)), x1 = bf2f((u16)(c01 >> 16));
        float x2 = bf2f((u16)(c23 & 0xffff)), x3 = bf2f((u16)(c23 >> 16));
        float ssq = (x0 * x0 + x1 * x1) + (x2 * x2 + x3 * x3);
        ssq += __shfl_xor(ssq, 1);
        ssq += __shfl_xor(ssq, 2);
        ssq += __shfl_xor(ssq, 4);
        ssq += __shfl_xor(ssq, 8);
        ssq += __shfl_xor(ssq, 16);
        float rr = rsqrtf(ssq * (1.0f / 128.0f) + 1e-6f);
        float nn0 = x0 * rr * wvv.x, nn1 = x1 * rr * wvv.y;
        float nn2 = x2 * rr * wvv.z, nn3 = x3 * rr * wvv.w;
        float p0 = __shfl_xor(nn0, 16), p1 = __shfl_xor(nn1, 16);
        float p2 = __shfl_xor(nn2, 16), p3 = __shfl_xor(nn3, 16);
        float sgn = (sl < 16) ? -1.0f : 1.0f;
        int tok = tok0 + r;
        const float4 cv = *(const float4*)(cosp + (size_t)tok * 128 + sl * 4);
        const float4 sv = *(const float4*)(sinp + (size_t)tok * 128 + sl * 4);
        float o0 = nn0 * cv.x + sgn * p0 * sv.x;
        float o1 = nn1 * cv.y + sgn * p1 * sv.y;
        float o2 = nn2 * cv.z + sgn * p2 * sv.z;
        float o3 = nn3 * cv.w + sgn * p3 * sv.w;
        if (isq) { o0 *= QSCALE; o1 *= QSCALE; o2 *= QSCALE; o3 *= QSCALE; }
        u32 lo = (u32)f2bf(o0) | ((u32)f2bf(o1) << 16);
        u32 hi = (u32)f2bf(o2) | ((u32)f2bf(o3) << 16);
        *(uint2*)(outp + (size_t)(l0q + r) * D_ + sl * 4) = make_uint2(lo, hi);
      }
    } else {
      // V: transpose to (B,KV,D,L) with key-permutation within 32-token groups
      int g = hq - 20;
      int d = tid >> 2, a2 = (tid >> 1) & 1, lh = tid & 1;
      u16* dst = Vtb + ((size_t)(bL * KV_ + g) * D_ + d) * L_ + l0q + lh * 64;
      for (int bc = 0; bc < 8; ++bc) {
        int b2 = bc & 1, c = bc >> 1;
        int ls = lh * 64 + a2 * 32 + 16 * b2 + 4 * c;
        u32 lo = (u32)Cs[ls * 136 + d] | ((u32)Cs[(ls + 1) * 136 + d] << 16);
        u32 hi = (u32)Cs[(ls + 2) * 136 + d] | ((u32)Cs[(ls + 3) * 136 + d] << 16);
        *(uint2*)(dst + a2 * 32 + 8 * c + 4 * b2) = make_uint2(lo, hi);
      }
    }
  }
}

// ---------------- bf16 GEMM: C(MxN) = A(MxK) @ Bt(NxK)^T, fp32 out ----------------
template <int OUT_BF16>
__global__ __launch_bounds__(256, 3) void k_gemm_bt(
    const u16* __restrict__ A, const u16* __restrict__ Bt, void* __restrict__ Cv,
    int M, int N, int K) {
  __shared__ u16 smem2[16384];
  u16* As = smem2;
  u16* Bs = smem2 + 8192;
  const int tid = threadIdx.x;
  const int wave = tid >> 6, lane = tid & 63;
  const int wr = wave >> 1, wc = wave & 1;
  const int quad = lane >> 4, fm = lane & 15;
  const int m0 = blockIdx.y * 128, n0 = blockIdx.x * 128;
  f32x4 acc[4][4];
  for (int i = 0; i < 4; ++i)
    for (int j = 0; j < 4; ++j)
      for (int r = 0; r < 4; ++r) acc[i][j][r] = 0.0f;

  const int lrow = lane >> 3;
  const int lcol = (lane & 7) * 8;
  const int fk = quad * 8;

  for (int kt = 0; kt < K; kt += 64) {
    for (int p = 0; p < 4; ++p) {
      int roff = wave * 32 + p * 8 + lrow;
      gl_lds16(A + (size_t)(m0 + roff) * K + kt + lcol,
               As + wave * 2048 + p * 512 + lane * 8);
      gl_lds16(Bt + (size_t)(n0 + roff) * K + kt + lcol,
               Bs + wave * 2048 + p * 512 + lane * 8);
    }
    __syncthreads();
    for (int s = 0; s < 2; ++s) {
      bf16x8 af[4], bfr[4];
      for (int i = 0; i < 4; ++i)
        af[i] = *(const bf16x8*)(As + (wr * 64 + i * 16 + fm) * 64 + s * 32 + fk);
      for (int j = 0; j < 4; ++j)
        bfr[j] = *(const bf16x8*)(Bs + (wc * 64 + j * 16 + fm) * 64 + s * 32 + fk);
      for (int i = 0; i < 4; ++i)
        for (int j = 0; j < 4; ++j)
          acc[i][j] = __builtin_amdgcn_mfma_f32_16x16x32_bf16(af[i], bfr[j],
                                                              acc[i][j], 0, 0, 0);
    }
    __syncthreads();
  }

  if (OUT_BF16) {
    u16* Cs = smem2;
    for (int hh = 0; hh < 2; ++hh) {
      if (hh) __syncthreads();
      if (wr == hh)
        for (int i = 0; i < 4; ++i)
          for (int j = 0; j < 4; ++j)
            for (int r = 0; r < 4; ++r)
              Cs[(i * 16 + quad * 4 + r) * 136 + wc * 64 + j * 16 + fm] =
                  f2bf(acc[i][j][r]);
      __syncthreads();
      for (int it = 0; it < 4; ++it) {
        int row = it * 16 + (tid >> 4);
        int col = (tid & 15) * 8;
        uint4 v = *(const uint4*)(Cs + row * 136 + col);
        *(uint4*)((u16*)Cv + (size_t)(m0 + hh * 64 + row) * N + n0 + col) = v;
      }
    }
  } else {
    float* Cf = (float*)smem2;
    for (int p = 0; p < 4; ++p) {
      if (p) __syncthreads();
      if (wr == (p >> 1))
        for (int ii = 0; ii < 2; ++ii) {
          int i = 2 * (p & 1) + ii;
          for (int j = 0; j < 4; ++j)
            for (int r = 0; r < 4; ++r)
              Cf[(ii * 16 + quad * 4 + r) * 132 + wc * 64 + j * 16 + fm] =
                  acc[i][j][r];
        }
      __syncthreads();
      for (int it = 0; it < 4; ++it) {
        int row = it * 8 + (tid >> 5);
        int col = (tid & 31) * 4;
        float4 v = *(const float4*)(Cf + row * 132 + col);
        *(float4*)((float*)Cv + (size_t)(m0 + p * 32 + row) * N + n0 + col) = v;
      }
    }
  }
}

// ---------------- flash attention (S^T, no-max softmax, 2 groups/wave, dbuf) ----------------
// 1D 512 blocks; xcd = bid&7 owns exactly one (b,g) K/V set (3MB < 4MB L2).
__global__ __launch_bounds__(256, 2) void k_attn(const u16* __restrict__ Qb,
                                                 const u16* __restrict__ Kb,
                                                 const u16* __restrict__ Vtb,
                                                 u16* __restrict__ AO) {
  __shared__ u16 smem3[32768];
  const int tid = threadIdx.x, wave = tid >> 6, lane = tid & 63;
  const int quad = lane >> 4, fm = lane & 15;
  const int f7 = fm & 7;
  const int bid = blockIdx.x;
  const int xcd = bid & 7, w = bid >> 3;
  const int b = xcd >> 2, g = xcd & 3;
  const int h = g * 4 + (w & 3);
  const int qt = w >> 2;
  const int bh = b * 16 + h;
  const u16* Kg = Kb + ((size_t)(b * KV_ + g)) * L_ * D_;
  const u16* Vg = Vtb + ((size_t)(b * KV_ + g)) * D_ * L_;

  const u16* Qg = Qb + ((size_t)bh * L_ + qt * 128 + wave * 32 + fm) * D_;
  bf16x8 qf1[4], qf2[4];
  for (int ks = 0; ks < 4; ++ks) {
    qf1[ks] = *(const bf16x8*)(Qg + ks * 32 + quad * 8);
    qf2[ks] = *(const bf16x8*)(Qg + 16 * D_ + ks * 32 + quad * 8);
  }

  f32x4 o1[8], o2[8];
  for (int f = 0; f < 8; ++f)
    for (int r = 0; r < 4; ++r) { o1[f][r] = 0.0f; o2[f][r] = 0.0f; }
  float lr1 = 0.0f, lr2 = 0.0f;
  const f32x4 fz = {0.0f, 0.0f, 0.0f, 0.0f};

  const int eK = wave * 2048 + (lane << 3);
  const int cK = lane & 15;
  const int cV = lane & 7;

#define STAGE(kt_, buf_)                                                      \
  {                                                                           \
    u16* Kd = smem3 + (buf_)*16384;                                           \
    u16* Vd = smem3 + (buf_)*16384 + 8192;                                    \
    for (int p = 0; p < 4; ++p) {                                             \
      int e = eK + p * 512;                                                   \
      int rowK = e >> 7;                                                      \
      int gK = (cK & 8) | ((cK & 7) ^ (rowK & 7));                            \
      gl_lds16(Kg + (size_t)((kt_)*64 + rowK) * 128 + gK * 8, Kd + e);        \
      int rowV = e >> 6;                                                      \
      int gV = cV ^ (rowV & 7);                                               \
      gl_lds16(Vg + (size_t)rowV * L_ + (kt_)*64 + gV * 8, Vd + e);           \
    }                                                                         \
  }

  STAGE(0, 0);
  for (int kt = 0; kt < 32; ++kt) {
    __syncthreads();
    if (kt + 1 < 32) STAGE(kt + 1, (kt + 1) & 1);
    const u16* Ks = smem3 + (kt & 1) * 16384;
    const u16* Vs = Ks + 8192;

    f32x4 s1[4], s2[4];
    __builtin_amdgcn_s_setprio(1);
    {
      int cp = (quad & 8) | (quad ^ f7);
      for (int n = 0; n < 4; ++n) {
        bf16x8 kf = *(const bf16x8*)(Ks + (n * 16 + fm) * 128 + cp * 8);
        s1[n] = __builtin_amdgcn_mfma_f32_16x16x32_bf16(kf, qf1[0], fz, 0, 0, 0);
        s2[n] = __builtin_amdgcn_mfma_f32_16x16x32_bf16(kf, qf2[0], fz, 0, 0, 0);
      }
    }
    for (int ks = 1; ks < 4; ++ks) {
      int c = 4 * ks + quad;
      int cp = (c & 8) | ((c & 7) ^ f7);
      for (int n = 0; n < 4; ++n) {
        bf16x8 kf = *(const bf16x8*)(Ks + (n * 16 + fm) * 128 + cp * 8);
        s1[n] = __builtin_amdgcn_mfma_f32_16x16x32_bf16(kf, qf1[ks], s1[n], 0, 0, 0);
        s2[n] = __builtin_amdgcn_mfma_f32_16x16x32_bf16(kf, qf2[ks], s2[n], 0, 0, 0);
      }
    }
    __builtin_amdgcn_s_setprio(0);

    u32 pk1[4][2], pk2[4][2];
    float rs1 = 0.0f, rs2 = 0.0f;
    for (int n = 0; n < 4; ++n) {
      float a0 = __builtin_amdgcn_exp2f(s1[n][0]);
      float a1 = __builtin_amdgcn_exp2f(s1[n][1]);
      float a2 = __builtin_amdgcn_exp2f(s1[n][2]);
      float a3 = __builtin_amdgcn_exp2f(s1[n][3]);
      rs1 += (a0 + a1) + (a2 + a3);
      pk1[n][0] = pkbf(a0, a1);
      pk1[n][1] = pkbf(a2, a3);
      float b0 = __builtin_amdgcn_exp2f(s2[n][0]);
      float b1 = __builtin_amdgcn_exp2f(s2[n][1]);
      float b2 = __builtin_amdgcn_exp2f(s2[n][2]);
      float b3 = __builtin_amdgcn_exp2f(s2[n][3]);
      rs2 += (b0 + b1) + (b2 + b3);
      pk2[n][0] = pkbf(b0, b1);
      pk2[n][1] = pkbf(b2, b3);
    }
    lr1 += rs1;
    lr2 += rs2;

    __builtin_amdgcn_s_setprio(1);
    for (int ks2 = 0; ks2 < 2; ++ks2) {
      union { u32 u[4]; bf16x8 v; } pa1, pa2;
      pa1.u[0] = pk1[2 * ks2][0];
      pa1.u[1] = pk1[2 * ks2][1];
      pa1.u[2] = pk1[2 * ks2 + 1][0];
      pa1.u[3] = pk1[2 * ks2 + 1][1];
      pa2.u[0] = pk2[2 * ks2][0];
      pa2.u[1] = pk2[2 * ks2][1];
      pa2.u[2] = pk2[2 * ks2 + 1][0];
      pa2.u[3] = pk2[2 * ks2 + 1][1];
      int chunk = (4 * ks2 + quad) ^ f7;
      for (int f = 0; f < 8; ++f) {
        bf16x8 vv = *(const bf16x8*)(Vs + (f * 16 + fm) * 64 + chunk * 8);
        o1[f] = __builtin_amdgcn_mfma_f32_16x16x32_bf16(pa1.v, vv, o1[f], 0, 0, 0);
        o2[f] = __builtin_amdgcn_mfma_f32_16x16x32_bf16(pa2.v, vv, o2[f], 0, 0, 0);
      }
    }
    __builtin_amdgcn_s_setprio(0);
  }
#undef STAGE

  const size_t tok0 = (size_t)b * L_ + qt * 128;
  for (int grp = 0; grp < 2; ++grp) {
    f32x4* o = grp ? o2 : o1;
    float lr = grp ? lr2 : lr1;
    lr += __shfl_xor(lr, 16);
    lr += __shfl_xor(lr, 32);
    float li = 1.0f / lr;
    float l0 = __shfl(li, (lane & 48) | (quad * 4 + 0));
    float l1 = __shfl(li, (lane & 48) | (quad * 4 + 1));
    float l2 = __shfl(li, (lane & 48) | (quad * 4 + 2));
    float l3 = __shfl(li, (lane & 48) | (quad * 4 + 3));
    __syncthreads();
    for (int f = 0; f < 8; ++f) {
      int e = (wave * 16 + quad * 4) * 136 + f * 16 + fm;
      smem3[e] = f2bf(o[f][0] * l0);
      smem3[e + 136] = f2bf(o[f][1] * l1);
      smem3[e + 272] = f2bf(o[f][2] * l2);
      smem3[e + 408] = f2bf(o[f][3] * l3);
    }
    __syncthreads();
    for (int it = 0; it < 8; ++it) {
      int crow = (tid >> 6) * 16 + it * 2 + (lane >> 5);
      int q = (crow >> 4) * 32 + grp * 16 + (crow & 15);
      int cc = (lane & 31) * 4;
      uint2 v = *(const uint2*)(smem3 + crow * 136 + cc);
      *(uint2*)(AO + (tok0 + q) * (H_ * D_) + h * D_ + cc) = v;
    }
  }
}

// ---------------- launcher ----------------
extern "C" void kernel_launch(void* const* d_in, const int* in_sizes, int n_in,
                              void* d_out, int out_size, void* d_ws,
                              size_t ws_size, hipStream_t stream) {
  const float* hidden = (const float*)d_in[0];
  const float* cosp = (const float*)d_in[1];
  const float* sinp = (const float*)d_in[2];
  const float* Wq = (const float*)d_in[3];
  const float* Wk = (const float*)d_in[4];
  const float* Wv = (const float*)d_in[5];
  const float* Wo = (const float*)d_in[6];
  const float* qw = (const float*)d_in[7];
  const float* kw = (const float*)d_in[8];
  float* out = (float*)d_out;

  char* w = (char*)d_ws;
  u16* Xb = (u16*)(w);                          // 4096x2048 bf16, 16MB
  u16* Wtqkv = (u16*)(w + (16u << 20));         // 3072x2048 bf16, 12MB
  u16* Wto = (u16*)(w + (28u << 20));           // 2048x2048 bf16, 8MB
  u16* Qb = (u16*)(w + (36u << 20));            // 16MB
  u16* Kb = (u16*)(w + (52u << 20));            // 4MB
  u16* Vtb = (u16*)(w + (56u << 20));           // 4MB (ends 60MB)
  u16* AO = Xb;                                 // reuse after gemm_qkv

  k_prep<<<18432, 256, 0, stream>>>(hidden, Xb, Wq, Wk, Wv, Wo, Wtqkv, Wto);
  k_gemm_qkv<<<dim3(192), dim3(512), 131072, stream>>>(Xb, Wtqkv, cosp, sinp,
                                                       qw, kw, Qb, Kb, Vtb);
  k_attn<<<dim3(512), 256, 0, stream>>>(Qb, Kb, Vtb, AO);
  k_gemm_bt<0><<<dim3(16, 32), 256, 0, stream>>>(AO, Wto, out, 4096, 2048, 2048);
}

// Round 5
// 306.266 us; speedup vs baseline: 1.0122x; 1.0122x over previous
//
#include <hip/hip_runtime.h>

typedef unsigned short u16;
typedef unsigned int u32;
typedef short bf16x8 __attribute__((ext_vector_type(8)));
typedef float f32x4 __attribute__((ext_vector_type(4)));

#define B_ 2
#define L_ 2048
#define H_ 16
#define KV_ 4
#define D_ 128
#define HID_ 2048

// 1/sqrt(128) * log2(e): folded into Q so softmax runs in exp2 domain.
#define QSCALE (0.08838834764831845f * 1.4426950408889634f)

__device__ __forceinline__ u16 f2bf(float f) {
  union { float f; u32 u; } v; v.f = f;
  u32 u = v.u;
  return (u16)((u + 0x7FFFu + ((u >> 16) & 1u)) >> 16);
}
__device__ __forceinline__ float bf2f(u16 h) {
  union { u32 u; float f; } v; v.u = ((u32)h) << 16;
  return v.f;
}
__device__ __forceinline__ u32 pkbf(float a, float b) {
  union { float f; u32 u; } x, y; x.f = a; y.f = b;
  return ((x.u + 0x8000u) >> 16) | ((y.u + 0x8000u) & 0xffff0000u);
}
__device__ __forceinline__ void gl_lds16(const void* g, void* l) {
  __builtin_amdgcn_global_load_lds((__attribute__((address_space(1))) void*)(g),
                                   (__attribute__((address_space(3))) void*)(l),
                                   16, 0, 0);
}

template <int N> __device__ __forceinline__ void vmwait() {
  asm volatile("s_waitcnt vmcnt(%0)" ::"n"(N) : "memory");
}
#define BARRIER()                                                         \
  do {                                                                    \
    asm volatile("" ::: "memory");                                        \
    __builtin_amdgcn_s_barrier();                                         \
    asm volatile("" ::: "memory");                                        \
    __builtin_amdgcn_sched_barrier(0);                                    \
  } while (0)

// ---------------- prep: fp32->bf16 X convert + all weight transposes ----------------
// Transpose write side vectorized: one uint2 (4 bf16) per thread instead of
// 4 scalar u16 stores (G13 applies to stores too).
__global__ void k_prep(const float* __restrict__ hidden, u16* __restrict__ Xb,
                       const float* __restrict__ Wq, const float* __restrict__ Wk,
                       const float* __restrict__ Wv, const float* __restrict__ Wo,
                       u16* __restrict__ Wtqkv, u16* __restrict__ Wto) {
  __shared__ float t[32][33];
  int id = blockIdx.x;
  if (id < 8192) {
    int i = id * 256 + threadIdx.x;
    float4 v = ((const float4*)hidden)[i];
    u32 a = (u32)f2bf(v.x) | ((u32)f2bf(v.y) << 16);
    u32 b = (u32)f2bf(v.z) | ((u32)f2bf(v.w) << 16);
    ((uint2*)Xb)[i] = make_uint2(a, b);
    return;
  }
  id -= 8192;
  const float* src; u16* dst; int C; int ct, rt;
  if (id < 4096)      { src = Wq; dst = Wtqkv;               C = 2048; ct = id & 63; rt = id >> 6; }
  else if (id < 5120) { id -= 4096; src = Wk; dst = Wtqkv + 2048 * 2048; C = 512; ct = id & 15; rt = id >> 4; }
  else if (id < 6144) { id -= 5120; src = Wv; dst = Wtqkv + 2560 * 2048; C = 512; ct = id & 15; rt = id >> 4; }
  else                { id -= 6144; src = Wo; dst = Wto;     C = 2048; ct = id & 63; rt = id >> 6; }
  const int R = 2048;
  int c0 = ct * 32, r0 = rt * 32;
  int tx = threadIdx.x & 31, ty = threadIdx.x >> 5;
  for (int i = ty; i < 32; i += 8)
    t[i][tx] = src[(size_t)(r0 + i) * C + c0 + tx];
  __syncthreads();
  // dst[c0+X][r0+Y] = t[Y][X]; thread -> (X = sc, Y = tg*4..tg*4+3), 8B store
  int sc = threadIdx.x >> 3;  // 0..31
  int tg = threadIdx.x & 7;   // 0..7
  u32 lo = (u32)f2bf(t[tg * 4 + 0][sc]) | ((u32)f2bf(t[tg * 4 + 1][sc]) << 16);
  u32 hi = (u32)f2bf(t[tg * 4 + 2][sc]) | ((u32)f2bf(t[tg * 4 + 3][sc]) << 16);
  *(uint2*)(dst + (size_t)(c0 + sc) * R + r0 + tg * 4) = make_uint2(lo, hi);
}

// ---------------- fused QKV GEMM (256^2, round-1 structure) + RMSnorm + RoPE + V-trans --
// C(4096x3072) = Xb @ Wtqkv^T. BM=BN=256, BK=64, 8 waves (2Mx4N), 128KB LDS dbuf.
// T2 swizzle via inverse-swizzled global source + swizzled ds_read. Counted
// vmcnt(4) at the 3 sync points per tile (never 0 in loop; drain 4->2->0 in
// peeled last tile). T5 setprio around MFMA clusters.
__global__ __launch_bounds__(512, 2) void k_gemm_qkv(
    const u16* __restrict__ A, const u16* __restrict__ Bt,
    const float* __restrict__ cosp, const float* __restrict__ sinp,
    const float* __restrict__ qw, const float* __restrict__ kw,
    u16* __restrict__ Qb, u16* __restrict__ Kb, u16* __restrict__ Vtb) {
  extern __shared__ char smem[];  // 131072B: A dbuf 2x32KB | B dbuf 2x32KB
  const int tid = threadIdx.x;
  const int wave = tid >> 6, lane = tid & 63;
  const int wm = wave >> 2, wn = wave & 3;
  const int quad = lane >> 4, fm = lane & 15;
  const int f7 = fm & 7;

  // bijective XCD swizzle: 192 blocks, xcd = bid&7 owns 2 consecutive by rows.
  const int bid = blockIdx.x;
  const int swz = (bid & 7) * 24 + (bid >> 3);
  const int by = swz / 12, bx = swz % 12;
  const int m0 = by * 256, n0 = bx * 256;

  const u16* Ag = A + (size_t)m0 * 2048;
  const u16* Bg = Bt + (size_t)n0 * 2048;
  const int schunk = (lane & 7) ^ ((lane >> 3) & 7);  // inverse-swizzled src chunk

  f32x4 acc[8][4];
#pragma unroll
  for (int i = 0; i < 8; ++i)
#pragma unroll
    for (int j = 0; j < 4; ++j)
#pragma unroll
      for (int r = 0; r < 4; ++r) acc[i][j][r] = 0.0f;

  bf16x8 af[4][2], bf[4][2];
  const int ArowB = (wm * 128 + fm) * 128;          // byte offset of A frag row
  const int BrowB = (wn * 64 + fm) * 128;           // byte offset of B frag row
  const int kc[2] = {(quad ^ f7) * 16, ((quad ^ 4) ^ f7) * 16};  // swizzled k-chunks

#define STAGE_A(qa_, kk_, bb_)                                               \
  _Pragma("unroll") for (int q = 0; q < 2; ++q) {                            \
    int ldsoff = (bb_)*32768 + q * 16384 + (qa_)*8192 + wave * 1024 + lane * 16; \
    int grow = q * 128 + (qa_)*64 + wave * 8 + (lane >> 3);                  \
    gl_lds16(Ag + (size_t)grow * 2048 + (kk_)*64 + schunk * 8, smem + ldsoff); \
  }
#define STAGE_B(qb_, kk_, bb_)                                               \
  _Pragma("unroll") for (int q = 0; q < 2; ++q) {                            \
    int gg = q * 2 + (wave >> 2);                                            \
    int ldsoff = 65536 + (bb_)*32768 + gg * 8192 + (qb_)*4096 +              \
                 (wave & 3) * 1024 + lane * 16;                              \
    int grow = gg * 64 + (qb_)*32 + (wave & 3) * 8 + (lane >> 3);            \
    gl_lds16(Bg + (size_t)grow * 2048 + (kk_)*64 + schunk * 8, smem + ldsoff); \
  }
#define LDA4(bb_, roff_)                                                     \
  _Pragma("unroll") for (int i = 0; i < 4; ++i)                              \
    _Pragma("unroll") for (int ks = 0; ks < 2; ++ks)                         \
      af[i][ks] = *(const bf16x8*)(smem + (bb_)*32768 + ArowB + (roff_) +    \
                                   i * 2048 + kc[ks]);
#define LDB2(bb_, j0_)                                                       \
  _Pragma("unroll") for (int j = 0; j < 2; ++j)                              \
    _Pragma("unroll") for (int ks = 0; ks < 2; ++ks)                         \
      bf[(j0_) + j][ks] = *(const bf16x8*)(smem + 65536 + (bb_)*32768 +      \
                                           BrowB + ((j0_) + j) * 2048 + kc[ks]);
#define MFMA_Q(I0_, J0_)                                                     \
  __builtin_amdgcn_s_setprio(1);                                             \
  _Pragma("unroll") for (int i = 0; i < 4; ++i)                              \
    _Pragma("unroll") for (int j = 0; j < 2; ++j)                            \
      _Pragma("unroll") for (int ks = 0; ks < 2; ++ks)                       \
        acc[(I0_) + i][(J0_) + j] = __builtin_amdgcn_mfma_f32_16x16x32_bf16( \
            af[i][ks], bf[(J0_) + j][ks], acc[(I0_) + i][(J0_) + j], 0, 0, 0); \
  __builtin_amdgcn_s_setprio(0);
#define TILE(kt_, bb_, ST_, W0_, W1_, W2_)                                   \
  {                                                                          \
    vmwait<W0_>(); BARRIER();                                                \
    LDA4(bb_, 0); LDB2(bb_, 0);                                              \
    if (ST_) { STAGE_A(0, (kt_) + 1, (bb_) ^ 1); }                           \
    MFMA_Q(0, 0);                                                            \
    vmwait<W1_>(); BARRIER();                                                \
    LDB2(bb_, 2);                                                            \
    if (ST_) { STAGE_B(0, (kt_) + 1, (bb_) ^ 1); }                           \
    MFMA_Q(0, 2);                                                            \
    vmwait<W2_>(); BARRIER();                                                \
    LDA4(bb_, 8192);                                                         \
    if (ST_) { STAGE_B(1, (kt_) + 1, (bb_) ^ 1); }                           \
    MFMA_Q(4, 0);                                                            \
    if (ST_) { STAGE_A(1, (kt_) + 1, (bb_) ^ 1); }                           \
    MFMA_Q(4, 2);                                                            \
  }

  // prologue: tile 0 fully staged, oldest-first in consumption order
  STAGE_A(0, 0, 0);
  STAGE_B(0, 0, 0);
  STAGE_B(1, 0, 0);
  STAGE_A(1, 0, 0);

#pragma unroll 1
  for (int t2 = 0; t2 < 30; t2 += 2) {
    TILE(t2, 0, 1, 4, 4, 4);
    TILE(t2 + 1, 1, 1, 4, 4, 4);
  }
  TILE(30, 0, 1, 4, 4, 4);
  TILE(31, 1, 0, 4, 2, 0);  // epilogue drain 4->2->0, no stage

#undef TILE
#undef MFMA_Q
#undef LDB2
#undef LDA4
#undef STAGE_B
#undef STAGE_A

  // ---- fused epilogue: 4 quarters, each = one head x 128 tokens ----
  u16* Cs = (u16*)smem;
  const int head2 = bx * 2;
  const int bL = by >> 3;
  const int l0 = m0 & 2047;
  __syncthreads();
#pragma unroll 1
  for (int qq = 0; qq < 4; ++qq) {
    const int qm = qq >> 1, qn = qq & 1;
    __syncthreads();
    if (wm == qm && (wn >> 1) == qn) {
#pragma unroll
      for (int i = 0; i < 8; ++i)
#pragma unroll
        for (int j = 0; j < 4; ++j)
#pragma unroll
          for (int r = 0; r < 4; ++r)
            Cs[(i * 16 + quad * 4 + r) * 136 + (wn & 1) * 64 + j * 16 + fm] =
                f2bf(acc[i][j][r]);
    }
    __syncthreads();
    const int hq = head2 + qn;
    const int tok0 = m0 + qm * 128;
    const int l0q = l0 + qm * 128;
    if (hq < 20) {
      const int isq = hq < 16;
      const float* wv = isq ? qw : kw;
      const int half = lane >> 5, sl = lane & 31;
      u16* outp = isq ? (Qb + (size_t)(bL * H_ + hq) * L_ * D_)
                      : (Kb + (size_t)(bL * KV_ + hq - 16) * L_ * D_);
      const float4 wvv = *(const float4*)(wv + sl * 4);
      for (int it = 0; it < 8; ++it) {
        int r = wave * 16 + it * 2 + half;
        const u16* crow = Cs + r * 136 + sl * 4;
        u32 c01 = *(const u32*)crow;
        u32 c23 = *(const u32*)(crow + 2);
        float x0 = bf2f((u16)(c01 & 0xffff)), x1 = bf2f((u16)(c01 >> 16));
        float x2 = bf2f((u16)(c23 & 0xffff)), x3 = bf2f((u16)(c23 >> 16));
        float ssq = (x0 * x0 + x1 * x1) + (x2 * x2 + x3 * x3);
        ssq += __shfl_xor(ssq, 1);
        ssq += __shfl_xor(ssq, 2);
        ssq += __shfl_xor(ssq, 4);
        ssq += __shfl_xor(ssq, 8);
        ssq += __shfl_xor(ssq, 16);
        float rr = rsqrtf(ssq * (1.0f / 128.0f) + 1e-6f);
        float nn0 = x0 * rr * wvv.x, nn1 = x1 * rr * wvv.y;
        float nn2 = x2 * rr * wvv.z, nn3 = x3 * rr * wvv.w;
        float p0 = __shfl_xor(nn0, 16), p1 = __shfl_xor(nn1, 16);
        float p2 = __shfl_xor(nn2, 16), p3 = __shfl_xor(nn3, 16);
        float sgn = (sl < 16) ? -1.0f : 1.0f;
        int tok = tok0 + r;
        const float4 cv = *(const float4*)(cosp + (size_t)tok * 128 + sl * 4);
        const float4 sv = *(const float4*)(sinp + (size_t)tok * 128 + sl * 4);
        float o0 = nn0 * cv.x + sgn * p0 * sv.x;
        float o1 = nn1 * cv.y + sgn * p1 * sv.y;
        float o2 = nn2 * cv.z + sgn * p2 * sv.z;
        float o3 = nn3 * cv.w + sgn * p3 * sv.w;
        if (isq) { o0 *= QSCALE; o1 *= QSCALE; o2 *= QSCALE; o3 *= QSCALE; }
        u32 lo = (u32)f2bf(o0) | ((u32)f2bf(o1) << 16);
        u32 hi = (u32)f2bf(o2) | ((u32)f2bf(o3) << 16);
        *(uint2*)(outp + (size_t)(l0q + r) * D_ + sl * 4) = make_uint2(lo, hi);
      }
    } else {
      // V: transpose to (B,KV,D,L) with key-permutation within 32-token groups
      int g = hq - 20;
      int d = tid >> 2, a2 = (tid >> 1) & 1, lh = tid & 1;
      u16* dst = Vtb + ((size_t)(bL * KV_ + g) * D_ + d) * L_ + l0q + lh * 64;
      for (int bc = 0; bc < 8; ++bc) {
        int b2 = bc & 1, c = bc >> 1;
        int ls = lh * 64 + a2 * 32 + 16 * b2 + 4 * c;
        u32 lo = (u32)Cs[ls * 136 + d] | ((u32)Cs[(ls + 1) * 136 + d] << 16);
        u32 hi = (u32)Cs[(ls + 2) * 136 + d] | ((u32)Cs[(ls + 3) * 136 + d] << 16);
        *(uint2*)(dst + a2 * 32 + 8 * c + 4 * b2) = make_uint2(lo, hi);
      }
    }
  }
}

// ---------------- bf16 GEMM: C(MxN) = A(MxK) @ Bt(NxK)^T, fp32 out ----------------
// fp32 epilogue: direct per-lane dword stores (4 rows x 64B segments per
// instruction) -- drops the 64KB LDS round-trip + 8 syncthreads per block.
template <int OUT_BF16>
__global__ __launch_bounds__(256, 3) void k_gemm_bt(
    const u16* __restrict__ A, const u16* __restrict__ Bt, void* __restrict__ Cv,
    int M, int N, int K) {
  __shared__ u16 smem2[16384];
  u16* As = smem2;
  u16* Bs = smem2 + 8192;
  const int tid = threadIdx.x;
  const int wave = tid >> 6, lane = tid & 63;
  const int wr = wave >> 1, wc = wave & 1;
  const int quad = lane >> 4, fm = lane & 15;
  const int m0 = blockIdx.y * 128, n0 = blockIdx.x * 128;
  f32x4 acc[4][4];
  for (int i = 0; i < 4; ++i)
    for (int j = 0; j < 4; ++j)
      for (int r = 0; r < 4; ++r) acc[i][j][r] = 0.0f;

  const int lrow = lane >> 3;
  const int lcol = (lane & 7) * 8;
  const int fk = quad * 8;

  for (int kt = 0; kt < K; kt += 64) {
    for (int p = 0; p < 4; ++p) {
      int roff = wave * 32 + p * 8 + lrow;
      gl_lds16(A + (size_t)(m0 + roff) * K + kt + lcol,
               As + wave * 2048 + p * 512 + lane * 8);
      gl_lds16(Bt + (size_t)(n0 + roff) * K + kt + lcol,
               Bs + wave * 2048 + p * 512 + lane * 8);
    }
    __syncthreads();
    for (int s = 0; s < 2; ++s) {
      bf16x8 af[4], bfr[4];
      for (int i = 0; i < 4; ++i)
        af[i] = *(const bf16x8*)(As + (wr * 64 + i * 16 + fm) * 64 + s * 32 + fk);
      for (int j = 0; j < 4; ++j)
        bfr[j] = *(const bf16x8*)(Bs + (wc * 64 + j * 16 + fm) * 64 + s * 32 + fk);
      for (int i = 0; i < 4; ++i)
        for (int j = 0; j < 4; ++j)
          acc[i][j] = __builtin_amdgcn_mfma_f32_16x16x32_bf16(af[i], bfr[j],
                                                              acc[i][j], 0, 0, 0);
    }
    __syncthreads();
  }

  if (OUT_BF16) {
    u16* Cs = smem2;
    for (int hh = 0; hh < 2; ++hh) {
      if (hh) __syncthreads();
      if (wr == hh)
        for (int i = 0; i < 4; ++i)
          for (int j = 0; j < 4; ++j)
            for (int r = 0; r < 4; ++r)
              Cs[(i * 16 + quad * 4 + r) * 136 + wc * 64 + j * 16 + fm] =
                  f2bf(acc[i][j][r]);
      __syncthreads();
      for (int it = 0; it < 4; ++it) {
        int row = it * 16 + (tid >> 4);
        int col = (tid & 15) * 8;
        uint4 v = *(const uint4*)(Cs + row * 136 + col);
        *(uint4*)((u16*)Cv + (size_t)(m0 + hh * 64 + row) * N + n0 + col) = v;
      }
    }
  } else {
    float* Cf = (float*)Cv;
#pragma unroll
    for (int i = 0; i < 4; ++i)
#pragma unroll
      for (int j = 0; j < 4; ++j)
#pragma unroll
        for (int r = 0; r < 4; ++r)
          Cf[(size_t)(m0 + wr * 64 + i * 16 + quad * 4 + r) * N + n0 + wc * 64 +
             j * 16 + fm] = acc[i][j][r];
  }
}

// ---------------- flash attention (S^T, no-max softmax, 2 groups/wave, dbuf) ----------------
// 1D 512 blocks; xcd = bid&7 owns exactly one (b,g) K/V set (3MB < 4MB L2).
__global__ __launch_bounds__(256, 2) void k_attn(const u16* __restrict__ Qb,
                                                 const u16* __restrict__ Kb,
                                                 const u16* __restrict__ Vtb,
                                                 u16* __restrict__ AO) {
  __shared__ u16 smem3[32768];
  const int tid = threadIdx.x, wave = tid >> 6, lane = tid & 63;
  const int quad = lane >> 4, fm = lane & 15;
  const int f7 = fm & 7;
  const int bid = blockIdx.x;
  const int xcd = bid & 7, w = bid >> 3;
  const int b = xcd >> 2, g = xcd & 3;
  const int h = g * 4 + (w & 3);
  const int qt = w >> 2;
  const int bh = b * 16 + h;
  const u16* Kg = Kb + ((size_t)(b * KV_ + g)) * L_ * D_;
  const u16* Vg = Vtb + ((size_t)(b * KV_ + g)) * D_ * L_;

  const u16* Qg = Qb + ((size_t)bh * L_ + qt * 128 + wave * 32 + fm) * D_;
  bf16x8 qf1[4], qf2[4];
  for (int ks = 0; ks < 4; ++ks) {
    qf1[ks] = *(const bf16x8*)(Qg + ks * 32 + quad * 8);
    qf2[ks] = *(const bf16x8*)(Qg + 16 * D_ + ks * 32 + quad * 8);
  }

  f32x4 o1[8], o2[8];
  for (int f = 0; f < 8; ++f)
    for (int r = 0; r < 4; ++r) { o1[f][r] = 0.0f; o2[f][r] = 0.0f; }
  float lr1 = 0.0f, lr2 = 0.0f;
  const f32x4 fz = {0.0f, 0.0f, 0.0f, 0.0f};

  const int eK = wave * 2048 + (lane << 3);
  const int cK = lane & 15;
  const int cV = lane & 7;

#define STAGE(kt_, buf_)                                                      \
  {                                                                           \
    u16* Kd = smem3 + (buf_)*16384;                                           \
    u16* Vd = smem3 + (buf_)*16384 + 8192;                                    \
    for (int p = 0; p < 4; ++p) {                                             \
      int e = eK + p * 512;                                                   \
      int rowK = e >> 7;                                                      \
      int gK = (cK & 8) | ((cK & 7) ^ (rowK & 7));                            \
      gl_lds16(Kg + (size_t)((kt_)*64 + rowK) * 128 + gK * 8, Kd + e);        \
      int rowV = e >> 6;                                                      \
      int gV = cV ^ (rowV & 7);                                               \
      gl_lds16(Vg + (size_t)rowV * L_ + (kt_)*64 + gV * 8, Vd + e);           \
    }                                                                         \
  }

  STAGE(0, 0);
  for (int kt = 0; kt < 32; ++kt) {
    __syncthreads();
    if (kt + 1 < 32) STAGE(kt + 1, (kt + 1) & 1);
    const u16* Ks = smem3 + (kt & 1) * 16384;
    const u16* Vs = Ks + 8192;

    f32x4 s1[4], s2[4];
    __builtin_amdgcn_s_setprio(1);
    {
      int cp = (quad & 8) | (quad ^ f7);
      for (int n = 0; n < 4; ++n) {
        bf16x8 kf = *(const bf16x8*)(Ks + (n * 16 + fm) * 128 + cp * 8);
        s1[n] = __builtin_amdgcn_mfma_f32_16x16x32_bf16(kf, qf1[0], fz, 0, 0, 0);
        s2[n] = __builtin_amdgcn_mfma_f32_16x16x32_bf16(kf, qf2[0], fz, 0, 0, 0);
      }
    }
    for (int ks = 1; ks < 4; ++ks) {
      int c = 4 * ks + quad;
      int cp = (c & 8) | ((c & 7) ^ f7);
      for (int n = 0; n < 4; ++n) {
        bf16x8 kf = *(const bf16x8*)(Ks + (n * 16 + fm) * 128 + cp * 8);
        s1[n] = __builtin_amdgcn_mfma_f32_16x16x32_bf16(kf, qf1[ks], s1[n], 0, 0, 0);
        s2[n] = __builtin_amdgcn_mfma_f32_16x16x32_bf16(kf, qf2[ks], s2[n], 0, 0, 0);
      }
    }
    __builtin_amdgcn_s_setprio(0);

    u32 pk1[4][2], pk2[4][2];
    float rs1 = 0.0f, rs2 = 0.0f;
    for (int n = 0; n < 4; ++n) {
      float a0 = __builtin_amdgcn_exp2f(s1[n][0]);
      float a1 = __builtin_amdgcn_exp2f(s1[n][1]);
      float a2 = __builtin_amdgcn_exp2f(s1[n][2]);
      float a3 = __builtin_amdgcn_exp2f(s1[n][3]);
      rs1 += (a0 + a1) + (a2 + a3);
      pk1[n][0] = pkbf(a0, a1);
      pk1[n][1] = pkbf(a2, a3);
      float b0 = __builtin_amdgcn_exp2f(s2[n][0]);
      float b1 = __builtin_amdgcn_exp2f(s2[n][1]);
      float b2 = __builtin_amdgcn_exp2f(s2[n][2]);
      float b3 = __builtin_amdgcn_exp2f(s2[n][3]);
      rs2 += (b0 + b1) + (b2 + b3);
      pk2[n][0] = pkbf(b0, b1);
      pk2[n][1] = pkbf(b2, b3);
    }
    lr1 += rs1;
    lr2 += rs2;

    __builtin_amdgcn_s_setprio(1);
    for (int ks2 = 0; ks2 < 2; ++ks2) {
      union { u32 u[4]; bf16x8 v; } pa1, pa2;
      pa1.u[0] = pk1[2 * ks2][0];
      pa1.u[1] = pk1[2 * ks2][1];
      pa1.u[2] = pk1[2 * ks2 + 1][0];
      pa1.u[3] = pk1[2 * ks2 + 1][1];
      pa2.u[0] = pk2[2 * ks2][0];
      pa2.u[1] = pk2[2 * ks2][1];
      pa2.u[2] = pk2[2 * ks2 + 1][0];
      pa2.u[3] = pk2[2 * ks2 + 1][1];
      int chunk = (4 * ks2 + quad) ^ f7;
      for (int f = 0; f < 8; ++f) {
        bf16x8 vv = *(const bf16x8*)(Vs + (f * 16 + fm) * 64 + chunk * 8);
        o1[f] = __builtin_amdgcn_mfma_f32_16x16x32_bf16(pa1.v, vv, o1[f], 0, 0, 0);
        o2[f] = __builtin_amdgcn_mfma_f32_16x16x32_bf16(pa2.v, vv, o2[f], 0, 0, 0);
      }
    }
    __builtin_amdgcn_s_setprio(0);
  }
#undef STAGE

  const size_t tok0 = (size_t)b * L_ + qt * 128;
  for (int grp = 0; grp < 2; ++grp) {
    f32x4* o = grp ? o2 : o1;
    float lr = grp ? lr2 : lr1;
    lr += __shfl_xor(lr, 16);
    lr += __shfl_xor(lr, 32);
    float li = 1.0f / lr;
    float l0 = __shfl(li, (lane & 48) | (quad * 4 + 0));
    float l1 = __shfl(li, (lane & 48) | (quad * 4 + 1));
    float l2 = __shfl(li, (lane & 48) | (quad * 4 + 2));
    float l3 = __shfl(li, (lane & 48) | (quad * 4 + 3));
    __syncthreads();
    for (int f = 0; f < 8; ++f) {
      int e = (wave * 16 + quad * 4) * 136 + f * 16 + fm;
      smem3[e] = f2bf(o[f][0] * l0);
      smem3[e + 136] = f2bf(o[f][1] * l1);
      smem3[e + 272] = f2bf(o[f][2] * l2);
      smem3[e + 408] = f2bf(o[f][3] * l3);
    }
    __syncthreads();
    for (int it = 0; it < 8; ++it) {
      int crow = (tid >> 6) * 16 + it * 2 + (lane >> 5);
      int q = (crow >> 4) * 32 + grp * 16 + (crow & 15);
      int cc = (lane & 31) * 4;
      uint2 v = *(const uint2*)(smem3 + crow * 136 + cc);
      *(uint2*)(AO + (tok0 + q) * (H_ * D_) + h * D_ + cc) = v;
    }
  }
}

// ---------------- launcher ----------------
extern "C" void kernel_launch(void* const* d_in, const int* in_sizes, int n_in,
                              void* d_out, int out_size, void* d_ws,
                              size_t ws_size, hipStream_t stream) {
  const float* hidden = (const float*)d_in[0];
  const float* cosp = (const float*)d_in[1];
  const float* sinp = (const float*)d_in[2];
  const float* Wq = (const float*)d_in[3];
  const float* Wk = (const float*)d_in[4];
  const float* Wv = (const float*)d_in[5];
  const float* Wo = (const float*)d_in[6];
  const float* qw = (const float*)d_in[7];
  const float* kw = (const float*)d_in[8];
  float* out = (float*)d_out;

  char* w = (char*)d_ws;
  u16* Xb = (u16*)(w);                          // 4096x2048 bf16, 16MB
  u16* Wtqkv = (u16*)(w + (16u << 20));         // 3072x2048 bf16, 12MB
  u16* Wto = (u16*)(w + (28u << 20));           // 2048x2048 bf16, 8MB
  u16* Qb = (u16*)(w + (36u << 20));            // 16MB
  u16* Kb = (u16*)(w + (52u << 20));            // 4MB
  u16* Vtb = (u16*)(w + (56u << 20));           // 4MB (ends 60MB)
  u16* AO = Xb;                                 // reuse after gemm_qkv

  k_prep<<<18432, 256, 0, stream>>>(hidden, Xb, Wq, Wk, Wv, Wo, Wtqkv, Wto);
  k_gemm_qkv<<<dim3(192), dim3(512), 131072, stream>>>(Xb, Wtqkv, cosp, sinp,
                                                       qw, kw, Qb, Kb, Vtb);
  k_attn<<<dim3(512), 256, 0, stream>>>(Qb, Kb, Vtb, AO);
  k_gemm_bt<0><<<dim3(16, 32), 256, 0, stream>>>(AO, Wto, out, 4096, 2048, 2048);
}

// Round 6
// 295.476 us; speedup vs baseline: 1.0492x; 1.0365x over previous
//
#include <hip/hip_runtime.h>

typedef unsigned short u16;
typedef unsigned int u32;
typedef short bf16x8 __attribute__((ext_vector_type(8)));
typedef float f32x4 __attribute__((ext_vector_type(4)));

#define B_ 2
#define L_ 2048
#define H_ 16
#define KV_ 4
#define D_ 128
#define HID_ 2048

// 1/sqrt(128) * log2(e): folded into Q so softmax runs in exp2 domain.
#define QSCALE (0.08838834764831845f * 1.4426950408889634f)

__device__ __forceinline__ u16 f2bf(float f) {
  union { float f; u32 u; } v; v.f = f;
  u32 u = v.u;
  return (u16)((u + 0x7FFFu + ((u >> 16) & 1u)) >> 16);
}
__device__ __forceinline__ float bf2f(u16 h) {
  union { u32 u; float f; } v; v.u = ((u32)h) << 16;
  return v.f;
}
__device__ __forceinline__ u32 pkbf(float a, float b) {
  union { float f; u32 u; } x, y; x.f = a; y.f = b;
  return ((x.u + 0x8000u) >> 16) | ((y.u + 0x8000u) & 0xffff0000u);
}
__device__ __forceinline__ void gl_lds16(const void* g, void* l) {
  __builtin_amdgcn_global_load_lds((__attribute__((address_space(1))) void*)(g),
                                   (__attribute__((address_space(3))) void*)(l),
                                   16, 0, 0);
}

template <int N> __device__ __forceinline__ void vmwait() {
  asm volatile("s_waitcnt vmcnt(%0)" ::"n"(N) : "memory");
}
#define BARRIER()                                                         \
  do {                                                                    \
    asm volatile("" ::: "memory");                                        \
    __builtin_amdgcn_s_barrier();                                         \
    asm volatile("" ::: "memory");                                        \
    __builtin_amdgcn_sched_barrier(0);                                    \
  } while (0)

// ---------------- prep: fp32->bf16 X convert + Wq/Wk/Wv transposes ----------------
// (Wo transpose moved into k_gemm_qkv's grid tail: it has no consumer until
// k_gemm_bt and qkv leaves ~64 CUs idle -- free overlap.)
// Transpose: float4 reads (16B/lane) + uint2 stores (8B/lane).
__global__ void k_prep(const float* __restrict__ hidden, u16* __restrict__ Xb,
                       const float* __restrict__ Wq, const float* __restrict__ Wk,
                       const float* __restrict__ Wv, u16* __restrict__ Wtqkv) {
  __shared__ float t[32][33];
  int id = blockIdx.x;
  if (id < 8192) {
    int i = id * 256 + threadIdx.x;
    float4 v = ((const float4*)hidden)[i];
    u32 a = (u32)f2bf(v.x) | ((u32)f2bf(v.y) << 16);
    u32 b = (u32)f2bf(v.z) | ((u32)f2bf(v.w) << 16);
    ((uint2*)Xb)[i] = make_uint2(a, b);
    return;
  }
  id -= 8192;
  const float* src; u16* dst; int C; int ct, rt;
  if (id < 4096)      { src = Wq; dst = Wtqkv;               C = 2048; ct = id & 63; rt = id >> 6; }
  else if (id < 5120) { id -= 4096; src = Wk; dst = Wtqkv + 2048 * 2048; C = 512; ct = id & 15; rt = id >> 4; }
  else                { id -= 5120; src = Wv; dst = Wtqkv + 2560 * 2048; C = 512; ct = id & 15; rt = id >> 4; }
  const int R = 2048;
  int c0 = ct * 32, r0 = rt * 32;
  int row = threadIdx.x >> 3, c4 = (threadIdx.x & 7) * 4;
  float4 v = *(const float4*)(src + (size_t)(r0 + row) * C + c0 + c4);
  t[row][c4 + 0] = v.x; t[row][c4 + 1] = v.y;
  t[row][c4 + 2] = v.z; t[row][c4 + 3] = v.w;
  __syncthreads();
  // dst[c0+X][r0+Y] = t[Y][X]; thread -> (X = sc, Y = tg*4..tg*4+3), 8B store
  int sc = threadIdx.x >> 3;  // 0..31
  int tg = threadIdx.x & 7;   // 0..7
  u32 lo = (u32)f2bf(t[tg * 4 + 0][sc]) | ((u32)f2bf(t[tg * 4 + 1][sc]) << 16);
  u32 hi = (u32)f2bf(t[tg * 4 + 2][sc]) | ((u32)f2bf(t[tg * 4 + 3][sc]) << 16);
  *(uint2*)(dst + (size_t)(c0 + sc) * R + r0 + tg * 4) = make_uint2(lo, hi);
}

// ---------------- fused QKV GEMM (256^2) + RMSnorm + RoPE + V-trans + Wo-transpose ----
// bid < 192: C(4096x3072) = Xb @ Wtqkv^T, BM=BN=256, BK=64, 8 waves, 128KB dbuf,
//   T2 swizzle (inverse-swizzled source + swizzled ds_read), counted vmcnt(4),
//   T5 setprio. bid >= 192: Wo transpose tiles on the CUs qkv leaves idle
//   (192 blocks < 512 slots); stream order makes Wto ready before k_gemm_bt.
__global__ __launch_bounds__(512, 2) void k_gemm_qkv(
    const u16* __restrict__ A, const u16* __restrict__ Bt,
    const float* __restrict__ cosp, const float* __restrict__ sinp,
    const float* __restrict__ qw, const float* __restrict__ kw,
    u16* __restrict__ Qb, u16* __restrict__ Kb, u16* __restrict__ Vtb,
    const float* __restrict__ Wo, u16* __restrict__ Wto) {
  extern __shared__ char smem[];  // 131072B: A dbuf 2x32KB | B dbuf 2x32KB
  const int tid = threadIdx.x;
  const int bid = blockIdx.x;

  if (bid >= 192) {
    // ---- Wo transpose: 512 blocks x 8 tiles (2 tiles/iter, 256-thread halves)
    float (*tt)[32][33] = (float(*)[32][33])smem;
    const int hf = tid >> 8;       // 0..1: which tile of the pair
    const int t2 = tid & 255;
    const int row = t2 >> 3, c4 = (t2 & 7) * 4;
    const int sc = t2 >> 3, tg = t2 & 7;
#pragma unroll 1
    for (int it = 0; it < 4; ++it) {
      int tile = (bid - 192) * 8 + it * 2 + hf;
      int ct = tile & 63, rt = tile >> 6;
      int c0 = ct * 32, r0 = rt * 32;
      float4 v = *(const float4*)(Wo + (size_t)(r0 + row) * 2048 + c0 + c4);
      __syncthreads();  // prior iter's LDS reads done before overwrite
      tt[hf][row][c4 + 0] = v.x; tt[hf][row][c4 + 1] = v.y;
      tt[hf][row][c4 + 2] = v.z; tt[hf][row][c4 + 3] = v.w;
      __syncthreads();
      u32 lo = (u32)f2bf(tt[hf][tg * 4 + 0][sc]) |
               ((u32)f2bf(tt[hf][tg * 4 + 1][sc]) << 16);
      u32 hi = (u32)f2bf(tt[hf][tg * 4 + 2][sc]) |
               ((u32)f2bf(tt[hf][tg * 4 + 3][sc]) << 16);
      *(uint2*)(Wto + (size_t)(c0 + sc) * 2048 + r0 + tg * 4) = make_uint2(lo, hi);
    }
    return;
  }

  const int wave = tid >> 6, lane = tid & 63;
  const int wm = wave >> 2, wn = wave & 3;
  const int quad = lane >> 4, fm = lane & 15;
  const int f7 = fm & 7;

  // bijective XCD swizzle: 192 blocks, xcd = bid&7 owns 2 consecutive by rows.
  const int swz = (bid & 7) * 24 + (bid >> 3);
  const int by = swz / 12, bx = swz % 12;
  const int m0 = by * 256, n0 = bx * 256;

  const u16* Ag = A + (size_t)m0 * 2048;
  const u16* Bg = Bt + (size_t)n0 * 2048;
  const int schunk = (lane & 7) ^ ((lane >> 3) & 7);  // inverse-swizzled src chunk

  f32x4 acc[8][4];
#pragma unroll
  for (int i = 0; i < 8; ++i)
#pragma unroll
    for (int j = 0; j < 4; ++j)
#pragma unroll
      for (int r = 0; r < 4; ++r) acc[i][j][r] = 0.0f;

  bf16x8 af[4][2], bf[4][2];
  const int ArowB = (wm * 128 + fm) * 128;          // byte offset of A frag row
  const int BrowB = (wn * 64 + fm) * 128;           // byte offset of B frag row
  const int kc[2] = {(quad ^ f7) * 16, ((quad ^ 4) ^ f7) * 16};  // swizzled k-chunks

#define STAGE_A(qa_, kk_, bb_)                                               \
  _Pragma("unroll") for (int q = 0; q < 2; ++q) {                            \
    int ldsoff = (bb_)*32768 + q * 16384 + (qa_)*8192 + wave * 1024 + lane * 16; \
    int grow = q * 128 + (qa_)*64 + wave * 8 + (lane >> 3);                  \
    gl_lds16(Ag + (size_t)grow * 2048 + (kk_)*64 + schunk * 8, smem + ldsoff); \
  }
#define STAGE_B(qb_, kk_, bb_)                                               \
  _Pragma("unroll") for (int q = 0; q < 2; ++q) {                            \
    int gg = q * 2 + (wave >> 2);                                            \
    int ldsoff = 65536 + (bb_)*32768 + gg * 8192 + (qb_)*4096 +              \
                 (wave & 3) * 1024 + lane * 16;                              \
    int grow = gg * 64 + (qb_)*32 + (wave & 3) * 8 + (lane >> 3);            \
    gl_lds16(Bg + (size_t)grow * 2048 + (kk_)*64 + schunk * 8, smem + ldsoff); \
  }
#define LDA4(bb_, roff_)                                                     \
  _Pragma("unroll") for (int i = 0; i < 4; ++i)                              \
    _Pragma("unroll") for (int ks = 0; ks < 2; ++ks)                         \
      af[i][ks] = *(const bf16x8*)(smem + (bb_)*32768 + ArowB + (roff_) +    \
                                   i * 2048 + kc[ks]);
#define LDB2(bb_, j0_)                                                       \
  _Pragma("unroll") for (int j = 0; j < 2; ++j)                              \
    _Pragma("unroll") for (int ks = 0; ks < 2; ++ks)                         \
      bf[(j0_) + j][ks] = *(const bf16x8*)(smem + 65536 + (bb_)*32768 +      \
                                           BrowB + ((j0_) + j) * 2048 + kc[ks]);
#define MFMA_Q(I0_, J0_)                                                     \
  __builtin_amdgcn_s_setprio(1);                                             \
  _Pragma("unroll") for (int i = 0; i < 4; ++i)                              \
    _Pragma("unroll") for (int j = 0; j < 2; ++j)                            \
      _Pragma("unroll") for (int ks = 0; ks < 2; ++ks)                       \
        acc[(I0_) + i][(J0_) + j] = __builtin_amdgcn_mfma_f32_16x16x32_bf16( \
            af[i][ks], bf[(J0_) + j][ks], acc[(I0_) + i][(J0_) + j], 0, 0, 0); \
  __builtin_amdgcn_s_setprio(0);
#define TILE(kt_, bb_, ST_, W0_, W1_, W2_)                                   \
  {                                                                          \
    vmwait<W0_>(); BARRIER();                                                \
    LDA4(bb_, 0); LDB2(bb_, 0);                                              \
    if (ST_) { STAGE_A(0, (kt_) + 1, (bb_) ^ 1); }                           \
    MFMA_Q(0, 0);                                                            \
    vmwait<W1_>(); BARRIER();                                                \
    LDB2(bb_, 2);                                                            \
    if (ST_) { STAGE_B(0, (kt_) + 1, (bb_) ^ 1); }                           \
    MFMA_Q(0, 2);                                                            \
    vmwait<W2_>(); BARRIER();                                                \
    LDA4(bb_, 8192);                                                         \
    if (ST_) { STAGE_B(1, (kt_) + 1, (bb_) ^ 1); }                           \
    MFMA_Q(4, 0);                                                            \
    if (ST_) { STAGE_A(1, (kt_) + 1, (bb_) ^ 1); }                           \
    MFMA_Q(4, 2);                                                            \
  }

  // prologue: tile 0 fully staged, oldest-first in consumption order
  STAGE_A(0, 0, 0);
  STAGE_B(0, 0, 0);
  STAGE_B(1, 0, 0);
  STAGE_A(1, 0, 0);

#pragma unroll 1
  for (int t2 = 0; t2 < 30; t2 += 2) {
    TILE(t2, 0, 1, 4, 4, 4);
    TILE(t2 + 1, 1, 1, 4, 4, 4);
  }
  TILE(30, 0, 1, 4, 4, 4);
  TILE(31, 1, 0, 4, 2, 0);  // epilogue drain 4->2->0, no stage

#undef TILE
#undef MFMA_Q
#undef LDB2
#undef LDA4
#undef STAGE_B
#undef STAGE_A

  // ---- fused epilogue: 4 quarters, each = one head x 128 tokens ----
  u16* Cs = (u16*)smem;
  const int head2 = bx * 2;
  const int bL = by >> 3;
  const int l0 = m0 & 2047;
  __syncthreads();
#pragma unroll 1
  for (int qq = 0; qq < 4; ++qq) {
    const int qm = qq >> 1, qn = qq & 1;
    __syncthreads();
    if (wm == qm && (wn >> 1) == qn) {
#pragma unroll
      for (int i = 0; i < 8; ++i)
#pragma unroll
        for (int j = 0; j < 4; ++j)
#pragma unroll
          for (int r = 0; r < 4; ++r)
            Cs[(i * 16 + quad * 4 + r) * 136 + (wn & 1) * 64 + j * 16 + fm] =
                f2bf(acc[i][j][r]);
    }
    __syncthreads();
    const int hq = head2 + qn;
    const int tok0 = m0 + qm * 128;
    const int l0q = l0 + qm * 128;
    if (hq < 20) {
      const int isq = hq < 16;
      const float* wv = isq ? qw : kw;
      const int half = lane >> 5, sl = lane & 31;
      u16* outp = isq ? (Qb + (size_t)(bL * H_ + hq) * L_ * D_)
                      : (Kb + (size_t)(bL * KV_ + hq - 16) * L_ * D_);
      const float4 wvv = *(const float4*)(wv + sl * 4);
      for (int it = 0; it < 8; ++it) {
        int r = wave * 16 + it * 2 + half;
        const u16* crow = Cs + r * 136 + sl * 4;
        u32 c01 = *(const u32*)crow;
        u32 c23 = *(const u32*)(crow + 2);
        float x0 = bf2f((u16)(c01 & 0xffff)), x1 = bf2f((u16)(c01 >> 16));
        float x2 = bf2f((u16)(c23 & 0xffff)), x3 = bf2f((u16)(c23 >> 16));
        float ssq = (x0 * x0 + x1 * x1) + (x2 * x2 + x3 * x3);
        ssq += __shfl_xor(ssq, 1);
        ssq += __shfl_xor(ssq, 2);
        ssq += __shfl_xor(ssq, 4);
        ssq += __shfl_xor(ssq, 8);
        ssq += __shfl_xor(ssq, 16);
        float rr = rsqrtf(ssq * (1.0f / 128.0f) + 1e-6f);
        float nn0 = x0 * rr * wvv.x, nn1 = x1 * rr * wvv.y;
        float nn2 = x2 * rr * wvv.z, nn3 = x3 * rr * wvv.w;
        float p0 = __shfl_xor(nn0, 16), p1 = __shfl_xor(nn1, 16);
        float p2 = __shfl_xor(nn2, 16), p3 = __shfl_xor(nn3, 16);
        float sgn = (sl < 16) ? -1.0f : 1.0f;
        int tok = tok0 + r;
        const float4 cv = *(const float4*)(cosp + (size_t)tok * 128 + sl * 4);
        const float4 sv = *(const float4*)(sinp + (size_t)tok * 128 + sl * 4);
        float o0 = nn0 * cv.x + sgn * p0 * sv.x;
        float o1 = nn1 * cv.y + sgn * p1 * sv.y;
        float o2 = nn2 * cv.z + sgn * p2 * sv.z;
        float o3 = nn3 * cv.w + sgn * p3 * sv.w;
        if (isq) { o0 *= QSCALE; o1 *= QSCALE; o2 *= QSCALE; o3 *= QSCALE; }
        u32 lo = (u32)f2bf(o0) | ((u32)f2bf(o1) << 16);
        u32 hi = (u32)f2bf(o2) | ((u32)f2bf(o3) << 16);
        *(uint2*)(outp + (size_t)(l0q + r) * D_ + sl * 4) = make_uint2(lo, hi);
      }
    } else {
      // V: transpose to (B,KV,D,L) with key-permutation within 32-token groups
      int g = hq - 20;
      int d = tid >> 2, a2 = (tid >> 1) & 1, lh = tid & 1;
      u16* dst = Vtb + ((size_t)(bL * KV_ + g) * D_ + d) * L_ + l0q + lh * 64;
      for (int bc = 0; bc < 8; ++bc) {
        int b2 = bc & 1, c = bc >> 1;
        int ls = lh * 64 + a2 * 32 + 16 * b2 + 4 * c;
        u32 lo = (u32)Cs[ls * 136 + d] | ((u32)Cs[(ls + 1) * 136 + d] << 16);
        u32 hi = (u32)Cs[(ls + 2) * 136 + d] | ((u32)Cs[(ls + 3) * 136 + d] << 16);
        *(uint2*)(dst + a2 * 32 + 8 * c + 4 * b2) = make_uint2(lo, hi);
      }
    }
  }
}

// ---------------- bf16 GEMM: C(MxN) = A(MxK) @ Bt(NxK)^T, fp32 out ----------------
// fp32 epilogue: direct per-lane dword stores (no LDS round-trip, no barriers).
template <int OUT_BF16>
__global__ __launch_bounds__(256, 3) void k_gemm_bt(
    const u16* __restrict__ A, const u16* __restrict__ Bt, void* __restrict__ Cv,
    int M, int N, int K) {
  __shared__ u16 smem2[16384];
  u16* As = smem2;
  u16* Bs = smem2 + 8192;
  const int tid = threadIdx.x;
  const int wave = tid >> 6, lane = tid & 63;
  const int wr = wave >> 1, wc = wave & 1;
  const int quad = lane >> 4, fm = lane & 15;
  const int m0 = blockIdx.y * 128, n0 = blockIdx.x * 128;
  f32x4 acc[4][4];
  for (int i = 0; i < 4; ++i)
    for (int j = 0; j < 4; ++j)
      for (int r = 0; r < 4; ++r) acc[i][j][r] = 0.0f;

  const int lrow = lane >> 3;
  const int lcol = (lane & 7) * 8;
  const int fk = quad * 8;

  for (int kt = 0; kt < K; kt += 64) {
    for (int p = 0; p < 4; ++p) {
      int roff = wave * 32 + p * 8 + lrow;
      gl_lds16(A + (size_t)(m0 + roff) * K + kt + lcol,
               As + wave * 2048 + p * 512 + lane * 8);
      gl_lds16(Bt + (size_t)(n0 + roff) * K + kt + lcol,
               Bs + wave * 2048 + p * 512 + lane * 8);
    }
    __syncthreads();
    for (int s = 0; s < 2; ++s) {
      bf16x8 af[4], bfr[4];
      for (int i = 0; i < 4; ++i)
        af[i] = *(const bf16x8*)(As + (wr * 64 + i * 16 + fm) * 64 + s * 32 + fk);
      for (int j = 0; j < 4; ++j)
        bfr[j] = *(const bf16x8*)(Bs + (wc * 64 + j * 16 + fm) * 64 + s * 32 + fk);
      for (int i = 0; i < 4; ++i)
        for (int j = 0; j < 4; ++j)
          acc[i][j] = __builtin_amdgcn_mfma_f32_16x16x32_bf16(af[i], bfr[j],
                                                              acc[i][j], 0, 0, 0);
    }
    __syncthreads();
  }

  if (OUT_BF16) {
    u16* Cs = smem2;
    for (int hh = 0; hh < 2; ++hh) {
      if (hh) __syncthreads();
      if (wr == hh)
        for (int i = 0; i < 4; ++i)
          for (int j = 0; j < 4; ++j)
            for (int r = 0; r < 4; ++r)
              Cs[(i * 16 + quad * 4 + r) * 136 + wc * 64 + j * 16 + fm] =
                  f2bf(acc[i][j][r]);
      __syncthreads();
      for (int it = 0; it < 4; ++it) {
        int row = it * 16 + (tid >> 4);
        int col = (tid & 15) * 8;
        uint4 v = *(const uint4*)(Cs + row * 136 + col);
        *(uint4*)((u16*)Cv + (size_t)(m0 + hh * 64 + row) * N + n0 + col) = v;
      }
    }
  } else {
    float* Cf = (float*)Cv;
#pragma unroll
    for (int i = 0; i < 4; ++i)
#pragma unroll
      for (int j = 0; j < 4; ++j)
#pragma unroll
        for (int r = 0; r < 4; ++r)
          Cf[(size_t)(m0 + wr * 64 + i * 16 + quad * 4 + r) * N + n0 + wc * 64 +
             j * 16 + fm] = acc[i][j][r];
  }
}

// ---------------- flash attention (S^T, no-max softmax, 2 groups/wave, dbuf) ----------------
// 1D 512 blocks; xcd = bid&7 owns exactly one (b,g) K/V set (3MB < 4MB L2).
__global__ __launch_bounds__(256, 2) void k_attn(const u16* __restrict__ Qb,
                                                 const u16* __restrict__ Kb,
                                                 const u16* __restrict__ Vtb,
                                                 u16* __restrict__ AO) {
  __shared__ u16 smem3[32768];
  const int tid = threadIdx.x, wave = tid >> 6, lane = tid & 63;
  const int quad = lane >> 4, fm = lane & 15;
  const int f7 = fm & 7;
  const int bid = blockIdx.x;
  const int xcd = bid & 7, w = bid >> 3;
  const int b = xcd >> 2, g = xcd & 3;
  const int h = g * 4 + (w & 3);
  const int qt = w >> 2;
  const int bh = b * 16 + h;
  const u16* Kg = Kb + ((size_t)(b * KV_ + g)) * L_ * D_;
  const u16* Vg = Vtb + ((size_t)(b * KV_ + g)) * D_ * L_;

  const u16* Qg = Qb + ((size_t)bh * L_ + qt * 128 + wave * 32 + fm) * D_;
  bf16x8 qf1[4], qf2[4];
  for (int ks = 0; ks < 4; ++ks) {
    qf1[ks] = *(const bf16x8*)(Qg + ks * 32 + quad * 8);
    qf2[ks] = *(const bf16x8*)(Qg + 16 * D_ + ks * 32 + quad * 8);
  }

  f32x4 o1[8], o2[8];
  for (int f = 0; f < 8; ++f)
    for (int r = 0; r < 4; ++r) { o1[f][r] = 0.0f; o2[f][r] = 0.0f; }
  float lr1 = 0.0f, lr2 = 0.0f;
  const f32x4 fz = {0.0f, 0.0f, 0.0f, 0.0f};

  const int eK = wave * 2048 + (lane << 3);
  const int cK = lane & 15;
  const int cV = lane & 7;

#define STAGE(kt_, buf_)                                                      \
  {                                                                           \
    u16* Kd = smem3 + (buf_)*16384;                                           \
    u16* Vd = smem3 + (buf_)*16384 + 8192;                                    \
    for (int p = 0; p < 4; ++p) {                                             \
      int e = eK + p * 512;                                                   \
      int rowK = e >> 7;                                                      \
      int gK = (cK & 8) | ((cK & 7) ^ (rowK & 7));                            \
      gl_lds16(Kg + (size_t)((kt_)*64 + rowK) * 128 + gK * 8, Kd + e);        \
      int rowV = e >> 6;                                                      \
      int gV = cV ^ (rowV & 7);                                               \
      gl_lds16(Vg + (size_t)rowV * L_ + (kt_)*64 + gV * 8, Vd + e);           \
    }                                                                         \
  }

  STAGE(0, 0);
  for (int kt = 0; kt < 32; ++kt) {
    __syncthreads();
    if (kt + 1 < 32) STAGE(kt + 1, (kt + 1) & 1);
    const u16* Ks = smem3 + (kt & 1) * 16384;
    const u16* Vs = Ks + 8192;

    f32x4 s1[4], s2[4];
    __builtin_amdgcn_s_setprio(1);
    {
      int cp = (quad & 8) | (quad ^ f7);
      for (int n = 0; n < 4; ++n) {
        bf16x8 kf = *(const bf16x8*)(Ks + (n * 16 + fm) * 128 + cp * 8);
        s1[n] = __builtin_amdgcn_mfma_f32_16x16x32_bf16(kf, qf1[0], fz, 0, 0, 0);
        s2[n] = __builtin_amdgcn_mfma_f32_16x16x32_bf16(kf, qf2[0], fz, 0, 0, 0);
      }
    }
    for (int ks = 1; ks < 4; ++ks) {
      int c = 4 * ks + quad;
      int cp = (c & 8) | ((c & 7) ^ f7);
      for (int n = 0; n < 4; ++n) {
        bf16x8 kf = *(const bf16x8*)(Ks + (n * 16 + fm) * 128 + cp * 8);
        s1[n] = __builtin_amdgcn_mfma_f32_16x16x32_bf16(kf, qf1[ks], s1[n], 0, 0, 0);
        s2[n] = __builtin_amdgcn_mfma_f32_16x16x32_bf16(kf, qf2[ks], s2[n], 0, 0, 0);
      }
    }
    __builtin_amdgcn_s_setprio(0);

    u32 pk1[4][2], pk2[4][2];
    float rs1 = 0.0f, rs2 = 0.0f;
    for (int n = 0; n < 4; ++n) {
      float a0 = __builtin_amdgcn_exp2f(s1[n][0]);
      float a1 = __builtin_amdgcn_exp2f(s1[n][1]);
      float a2 = __builtin_amdgcn_exp2f(s1[n][2]);
      float a3 = __builtin_amdgcn_exp2f(s1[n][3]);
      rs1 += (a0 + a1) + (a2 + a3);
      pk1[n][0] = pkbf(a0, a1);
      pk1[n][1] = pkbf(a2, a3);
      float b0 = __builtin_amdgcn_exp2f(s2[n][0]);
      float b1 = __builtin_amdgcn_exp2f(s2[n][1]);
      float b2 = __builtin_amdgcn_exp2f(s2[n][2]);
      float b3 = __builtin_amdgcn_exp2f(s2[n][3]);
      rs2 += (b0 + b1) + (b2 + b3);
      pk2[n][0] = pkbf(b0, b1);
      pk2[n][1] = pkbf(b2, b3);
    }
    lr1 += rs1;
    lr2 += rs2;

    __builtin_amdgcn_s_setprio(1);
    for (int ks2 = 0; ks2 < 2; ++ks2) {
      union { u32 u[4]; bf16x8 v; } pa1, pa2;
      pa1.u[0] = pk1[2 * ks2][0];
      pa1.u[1] = pk1[2 * ks2][1];
      pa1.u[2] = pk1[2 * ks2 + 1][0];
      pa1.u[3] = pk1[2 * ks2 + 1][1];
      pa2.u[0] = pk2[2 * ks2][0];
      pa2.u[1] = pk2[2 * ks2][1];
      pa2.u[2] = pk2[2 * ks2 + 1][0];
      pa2.u[3] = pk2[2 * ks2 + 1][1];
      int chunk = (4 * ks2 + quad) ^ f7;
      for (int f = 0; f < 8; ++f) {
        bf16x8 vv = *(const bf16x8*)(Vs + (f * 16 + fm) * 64 + chunk * 8);
        o1[f] = __builtin_amdgcn_mfma_f32_16x16x32_bf16(pa1.v, vv, o1[f], 0, 0, 0);
        o2[f] = __builtin_amdgcn_mfma_f32_16x16x32_bf16(pa2.v, vv, o2[f], 0, 0, 0);
      }
    }
    __builtin_amdgcn_s_setprio(0);
  }
#undef STAGE

  const size_t tok0 = (size_t)b * L_ + qt * 128;
  for (int grp = 0; grp < 2; ++grp) {
    f32x4* o = grp ? o2 : o1;
    float lr = grp ? lr2 : lr1;
    lr += __shfl_xor(lr, 16);
    lr += __shfl_xor(lr, 32);
    float li = 1.0f / lr;
    float l0 = __shfl(li, (lane & 48) | (quad * 4 + 0));
    float l1 = __shfl(li, (lane & 48) | (quad * 4 + 1));
    float l2 = __shfl(li, (lane & 48) | (quad * 4 + 2));
    float l3 = __shfl(li, (lane & 48) | (quad * 4 + 3));
    __syncthreads();
    for (int f = 0; f < 8; ++f) {
      int e = (wave * 16 + quad * 4) * 136 + f * 16 + fm;
      smem3[e] = f2bf(o[f][0] * l0);
      smem3[e + 136] = f2bf(o[f][1] * l1);
      smem3[e + 272] = f2bf(o[f][2] * l2);
      smem3[e + 408] = f2bf(o[f][3] * l3);
    }
    __syncthreads();
    for (int it = 0; it < 8; ++it) {
      int crow = (tid >> 6) * 16 + it * 2 + (lane >> 5);
      int q = (crow >> 4) * 32 + grp * 16 + (crow & 15);
      int cc = (lane & 31) * 4;
      uint2 v = *(const uint2*)(smem3 + crow * 136 + cc);
      *(uint2*)(AO + (tok0 + q) * (H_ * D_) + h * D_ + cc) = v;
    }
  }
}

// ---------------- launcher ----------------
extern "C" void kernel_launch(void* const* d_in, const int* in_sizes, int n_in,
                              void* d_out, int out_size, void* d_ws,
                              size_t ws_size, hipStream_t stream) {
  const float* hidden = (const float*)d_in[0];
  const float* cosp = (const float*)d_in[1];
  const float* sinp = (const float*)d_in[2];
  const float* Wq = (const float*)d_in[3];
  const float* Wk = (const float*)d_in[4];
  const float* Wv = (const float*)d_in[5];
  const float* Wo = (const float*)d_in[6];
  const float* qw = (const float*)d_in[7];
  const float* kw = (const float*)d_in[8];
  float* out = (float*)d_out;

  char* w = (char*)d_ws;
  u16* Xb = (u16*)(w);                          // 4096x2048 bf16, 16MB
  u16* Wtqkv = (u16*)(w + (16u << 20));         // 3072x2048 bf16, 12MB
  u16* Wto = (u16*)(w + (28u << 20));           // 2048x2048 bf16, 8MB
  u16* Qb = (u16*)(w + (36u << 20));            // 16MB
  u16* Kb = (u16*)(w + (52u << 20));            // 4MB
  u16* Vtb = (u16*)(w + (56u << 20));           // 4MB (ends 60MB)
  u16* AO = Xb;                                 // reuse after gemm_qkv

  k_prep<<<14336, 256, 0, stream>>>(hidden, Xb, Wq, Wk, Wv, Wtqkv);
  k_gemm_qkv<<<dim3(704), dim3(512), 131072, stream>>>(Xb, Wtqkv, cosp, sinp,
                                                       qw, kw, Qb, Kb, Vtb,
                                                       Wo, Wto);
  k_attn<<<dim3(512), 256, 0, stream>>>(Qb, Kb, Vtb, AO);
  k_gemm_bt<0><<<dim3(16, 32), 256, 0, stream>>>(AO, Wto, out, 4096, 2048, 2048);
}

// Round 15
// 294.906 us; speedup vs baseline: 1.0512x; 1.0019x over previous
//
#include <hip/hip_runtime.h>

typedef unsigned short u16;
typedef unsigned int u32;
typedef short bf16x8 __attribute__((ext_vector_type(8)));
typedef float f32x4 __attribute__((ext_vector_type(4)));

#define B_ 2
#define L_ 2048
#define H_ 16
#define KV_ 4
#define D_ 128
#define HID_ 2048

// 1/sqrt(128) * log2(e): folded into Q so softmax runs in exp2 domain.
#define QSCALE (0.08838834764831845f * 1.4426950408889634f)

__device__ __forceinline__ u16 f2bf(float f) {
  union { float f; u32 u; } v; v.f = f;
  u32 u = v.u;
  return (u16)((u + 0x7FFFu + ((u >> 16) & 1u)) >> 16);
}
__device__ __forceinline__ float bf2f(u16 h) {
  union { u32 u; float f; } v; v.u = ((u32)h) << 16;
  return v.f;
}
__device__ __forceinline__ u32 pkbf(float a, float b) {
  union { float f; u32 u; } x, y; x.f = a; y.f = b;
  return ((x.u + 0x8000u) >> 16) | ((y.u + 0x8000u) & 0xffff0000u);
}
__device__ __forceinline__ void gl_lds16(const void* g, void* l) {
  __builtin_amdgcn_global_load_lds((__attribute__((address_space(1))) void*)(g),
                                   (__attribute__((address_space(3))) void*)(l),
                                   16, 0, 0);
}

template <int N> __device__ __forceinline__ void vmwait() {
  asm volatile("s_waitcnt vmcnt(%0)" ::"n"(N) : "memory");
}
#define BARRIER()                                                         \
  do {                                                                    \
    asm volatile("" ::: "memory");                                        \
    __builtin_amdgcn_s_barrier();                                         \
    asm volatile("" ::: "memory");                                        \
    __builtin_amdgcn_sched_barrier(0);                                    \
  } while (0)

// ---------------- prep: fp32->bf16 X convert + Wq/Wk/Wv transposes ----------------
__global__ void k_prep(const float* __restrict__ hidden, u16* __restrict__ Xb,
                       const float* __restrict__ Wq, const float* __restrict__ Wk,
                       const float* __restrict__ Wv, u16* __restrict__ Wtqkv) {
  __shared__ float t[32][33];
  int id = blockIdx.x;
  if (id < 8192) {
    int i = id * 256 + threadIdx.x;
    float4 v = ((const float4*)hidden)[i];
    u32 a = (u32)f2bf(v.x) | ((u32)f2bf(v.y) << 16);
    u32 b = (u32)f2bf(v.z) | ((u32)f2bf(v.w) << 16);
    ((uint2*)Xb)[i] = make_uint2(a, b);
    return;
  }
  id -= 8192;
  const float* src; u16* dst; int C; int ct, rt;
  if (id < 4096)      { src = Wq; dst = Wtqkv;               C = 2048; ct = id & 63; rt = id >> 6; }
  else if (id < 5120) { id -= 4096; src = Wk; dst = Wtqkv + 2048 * 2048; C = 512; ct = id & 15; rt = id >> 4; }
  else                { id -= 5120; src = Wv; dst = Wtqkv + 2560 * 2048; C = 512; ct = id & 15; rt = id >> 4; }
  const int R = 2048;
  int c0 = ct * 32, r0 = rt * 32;
  int row = threadIdx.x >> 3, c4 = (threadIdx.x & 7) * 4;
  float4 v = *(const float4*)(src + (size_t)(r0 + row) * C + c0 + c4);
  t[row][c4 + 0] = v.x; t[row][c4 + 1] = v.y;
  t[row][c4 + 2] = v.z; t[row][c4 + 3] = v.w;
  __syncthreads();
  int sc = threadIdx.x >> 3;  // 0..31
  int tg = threadIdx.x & 7;   // 0..7
  u32 lo = (u32)f2bf(t[tg * 4 + 0][sc]) | ((u32)f2bf(t[tg * 4 + 1][sc]) << 16);
  u32 hi = (u32)f2bf(t[tg * 4 + 2][sc]) | ((u32)f2bf(t[tg * 4 + 3][sc]) << 16);
  *(uint2*)(dst + (size_t)(c0 + sc) * R + r0 + tg * 4) = make_uint2(lo, hi);
}

// ---------------- fused QKV GEMM (256^2) + RMSnorm + RoPE + V-trans + Wo-transpose ----
// bid < 192: GEMM. bid >= 192: Wo transpose tiles on the CUs qkv leaves idle.
__global__ __launch_bounds__(512, 2) void k_gemm_qkv(
    const u16* __restrict__ A, const u16* __restrict__ Bt,
    const float* __restrict__ cosp, const float* __restrict__ sinp,
    const float* __restrict__ qw, const float* __restrict__ kw,
    u16* __restrict__ Qb, u16* __restrict__ Kb, u16* __restrict__ Vtb,
    const float* __restrict__ Wo, u16* __restrict__ Wto) {
  extern __shared__ char smem[];  // 131072B: A dbuf 2x32KB | B dbuf 2x32KB
  const int tid = threadIdx.x;
  const int bid = blockIdx.x;

  if (bid >= 192) {
    float (*tt)[32][33] = (float(*)[32][33])smem;
    const int hf = tid >> 8;
    const int t2 = tid & 255;
    const int row = t2 >> 3, c4 = (t2 & 7) * 4;
    const int sc = t2 >> 3, tg = t2 & 7;
#pragma unroll 1
    for (int it = 0; it < 4; ++it) {
      int tile = (bid - 192) * 8 + it * 2 + hf;
      int ct = tile & 63, rt = tile >> 6;
      int c0 = ct * 32, r0 = rt * 32;
      float4 v = *(const float4*)(Wo + (size_t)(r0 + row) * 2048 + c0 + c4);
      __syncthreads();
      tt[hf][row][c4 + 0] = v.x; tt[hf][row][c4 + 1] = v.y;
      tt[hf][row][c4 + 2] = v.z; tt[hf][row][c4 + 3] = v.w;
      __syncthreads();
      u32 lo = (u32)f2bf(tt[hf][tg * 4 + 0][sc]) |
               ((u32)f2bf(tt[hf][tg * 4 + 1][sc]) << 16);
      u32 hi = (u32)f2bf(tt[hf][tg * 4 + 2][sc]) |
               ((u32)f2bf(tt[hf][tg * 4 + 3][sc]) << 16);
      *(uint2*)(Wto + (size_t)(c0 + sc) * 2048 + r0 + tg * 4) = make_uint2(lo, hi);
    }
    return;
  }

  const int wave = tid >> 6, lane = tid & 63;
  const int wm = wave >> 2, wn = wave & 3;
  const int quad = lane >> 4, fm = lane & 15;
  const int f7 = fm & 7;

  const int swz = (bid & 7) * 24 + (bid >> 3);
  const int by = swz / 12, bx = swz % 12;
  const int m0 = by * 256, n0 = bx * 256;

  const u16* Ag = A + (size_t)m0 * 2048;
  const u16* Bg = Bt + (size_t)n0 * 2048;
  const int schunk = (lane & 7) ^ ((lane >> 3) & 7);

  f32x4 acc[8][4];
#pragma unroll
  for (int i = 0; i < 8; ++i)
#pragma unroll
    for (int j = 0; j < 4; ++j)
#pragma unroll
      for (int r = 0; r < 4; ++r) acc[i][j][r] = 0.0f;

  bf16x8 af[4][2], bf[4][2];
  const int ArowB = (wm * 128 + fm) * 128;
  const int BrowB = (wn * 64 + fm) * 128;
  const int kc[2] = {(quad ^ f7) * 16, ((quad ^ 4) ^ f7) * 16};

#define STAGE_A(qa_, kk_, bb_)                                               \
  _Pragma("unroll") for (int q = 0; q < 2; ++q) {                            \
    int ldsoff = (bb_)*32768 + q * 16384 + (qa_)*8192 + wave * 1024 + lane * 16; \
    int grow = q * 128 + (qa_)*64 + wave * 8 + (lane >> 3);                  \
    gl_lds16(Ag + (size_t)grow * 2048 + (kk_)*64 + schunk * 8, smem + ldsoff); \
  }
#define STAGE_B(qb_, kk_, bb_)                                               \
  _Pragma("unroll") for (int q = 0; q < 2; ++q) {                            \
    int gg = q * 2 + (wave >> 2);                                            \
    int ldsoff = 65536 + (bb_)*32768 + gg * 8192 + (qb_)*4096 +              \
                 (wave & 3) * 1024 + lane * 16;                              \
    int grow = gg * 64 + (qb_)*32 + (wave & 3) * 8 + (lane >> 3);            \
    gl_lds16(Bg + (size_t)grow * 2048 + (kk_)*64 + schunk * 8, smem + ldsoff); \
  }
#define LDA4(bb_, roff_)                                                     \
  _Pragma("unroll") for (int i = 0; i < 4; ++i)                              \
    _Pragma("unroll") for (int ks = 0; ks < 2; ++ks)                         \
      af[i][ks] = *(const bf16x8*)(smem + (bb_)*32768 + ArowB + (roff_) +    \
                                   i * 2048 + kc[ks]);
#define LDB2(bb_, j0_)                                                       \
  _Pragma("unroll") for (int j = 0; j < 2; ++j)                              \
    _Pragma("unroll") for (int ks = 0; ks < 2; ++ks)                         \
      bf[(j0_) + j][ks] = *(const bf16x8*)(smem + 65536 + (bb_)*32768 +      \
                                           BrowB + ((j0_) + j) * 2048 + kc[ks]);
#define MFMA_Q(I0_, J0_)                                                     \
  __builtin_amdgcn_s_setprio(1);                                             \
  _Pragma("unroll") for (int i = 0; i < 4; ++i)                              \
    _Pragma("unroll") for (int j = 0; j < 2; ++j)                            \
      _Pragma("unroll") for (int ks = 0; ks < 2; ++ks)                       \
        acc[(I0_) + i][(J0_) + j] = __builtin_amdgcn_mfma_f32_16x16x32_bf16( \
            af[i][ks], bf[(J0_) + j][ks], acc[(I0_) + i][(J0_) + j], 0, 0, 0); \
  __builtin_amdgcn_s_setprio(0);
#define TILE(kt_, bb_, ST_, W0_, W1_, W2_)                                   \
  {                                                                          \
    vmwait<W0_>(); BARRIER();                                                \
    LDA4(bb_, 0); LDB2(bb_, 0);                                              \
    if (ST_) { STAGE_A(0, (kt_) + 1, (bb_) ^ 1); }                           \
    MFMA_Q(0, 0);                                                            \
    vmwait<W1_>(); BARRIER();                                                \
    LDB2(bb_, 2);                                                            \
    if (ST_) { STAGE_B(0, (kt_) + 1, (bb_) ^ 1); }                           \
    MFMA_Q(0, 2);                                                            \
    vmwait<W2_>(); BARRIER();                                                \
    LDA4(bb_, 8192);                                                         \
    if (ST_) { STAGE_B(1, (kt_) + 1, (bb_) ^ 1); }                           \
    MFMA_Q(4, 0);                                                            \
    if (ST_) { STAGE_A(1, (kt_) + 1, (bb_) ^ 1); }                           \
    MFMA_Q(4, 2);                                                            \
  }

  STAGE_A(0, 0, 0);
  STAGE_B(0, 0, 0);
  STAGE_B(1, 0, 0);
  STAGE_A(1, 0, 0);

#pragma unroll 1
  for (int t2 = 0; t2 < 30; t2 += 2) {
    TILE(t2, 0, 1, 4, 4, 4);
    TILE(t2 + 1, 1, 1, 4, 4, 4);
  }
  TILE(30, 0, 1, 4, 4, 4);
  TILE(31, 1, 0, 4, 2, 0);

#undef TILE
#undef MFMA_Q
#undef LDB2
#undef LDA4
#undef STAGE_B
#undef STAGE_A

  u16* Cs = (u16*)smem;
  const int head2 = bx * 2;
  const int bL = by >> 3;
  const int l0 = m0 & 2047;
  __syncthreads();
#pragma unroll 1
  for (int qq = 0; qq < 4; ++qq) {
    const int qm = qq >> 1, qn = qq & 1;
    __syncthreads();
    if (wm == qm && (wn >> 1) == qn) {
#pragma unroll
      for (int i = 0; i < 8; ++i)
#pragma unroll
        for (int j = 0; j < 4; ++j)
#pragma unroll
          for (int r = 0; r < 4; ++r)
            Cs[(i * 16 + quad * 4 + r) * 136 + (wn & 1) * 64 + j * 16 + fm] =
                f2bf(acc[i][j][r]);
    }
    __syncthreads();
    const int hq = head2 + qn;
    const int tok0 = m0 + qm * 128;
    const int l0q = l0 + qm * 128;
    if (hq < 20) {
      const int isq = hq < 16;
      const float* wv = isq ? qw : kw;
      const int half = lane >> 5, sl = lane & 31;
      u16* outp = isq ? (Qb + (size_t)(bL * H_ + hq) * L_ * D_)
                      : (Kb + (size_t)(bL * KV_ + hq - 16) * L_ * D_);
      const float4 wvv = *(const float4*)(wv + sl * 4);
      for (int it = 0; it < 8; ++it) {
        int r = wave * 16 + it * 2 + half;
        const u16* crow = Cs + r * 136 + sl * 4;
        u32 c01 = *(const u32*)crow;
        u32 c23 = *(const u32*)(crow + 2);
        float x0 = bf2f((u16)(c01 & 0xffff)), x1 = bf2f((u16)(c01 >> 16));
        float x2 = bf2f((u16)(c23 & 0xffff)), x3 = bf2f((u16)(c23 >> 16));
        float ssq = (x0 * x0 + x1 * x1) + (x2 * x2 + x3 * x3);
        ssq += __shfl_xor(ssq, 1);
        ssq += __shfl_xor(ssq, 2);
        ssq += __shfl_xor(ssq, 4);
        ssq += __shfl_xor(ssq, 8);
        ssq += __shfl_xor(ssq, 16);
        float rr = rsqrtf(ssq * (1.0f / 128.0f) + 1e-6f);
        float nn0 = x0 * rr * wvv.x, nn1 = x1 * rr * wvv.y;
        float nn2 = x2 * rr * wvv.z, nn3 = x3 * rr * wvv.w;
        float p0 = __shfl_xor(nn0, 16), p1 = __shfl_xor(nn1, 16);
        float p2 = __shfl_xor(nn2, 16), p3 = __shfl_xor(nn3, 16);
        float sgn = (sl < 16) ? -1.0f : 1.0f;
        int tok = tok0 + r;
        const float4 cv = *(const float4*)(cosp + (size_t)tok * 128 + sl * 4);
        const float4 sv = *(const float4*)(sinp + (size_t)tok * 128 + sl * 4);
        float o0 = nn0 * cv.x + sgn * p0 * sv.x;
        float o1 = nn1 * cv.y + sgn * p1 * sv.y;
        float o2 = nn2 * cv.z + sgn * p2 * sv.z;
        float o3 = nn3 * cv.w + sgn * p3 * sv.w;
        if (isq) { o0 *= QSCALE; o1 *= QSCALE; o2 *= QSCALE; o3 *= QSCALE; }
        u32 lo = (u32)f2bf(o0) | ((u32)f2bf(o1) << 16);
        u32 hi = (u32)f2bf(o2) | ((u32)f2bf(o3) << 16);
        *(uint2*)(outp + (size_t)(l0q + r) * D_ + sl * 4) = make_uint2(lo, hi);
      }
    } else {
      int g = hq - 20;
      int d = tid >> 2, a2 = (tid >> 1) & 1, lh = tid & 1;
      u16* dst = Vtb + ((size_t)(bL * KV_ + g) * D_ + d) * L_ + l0q + lh * 64;
      for (int bc = 0; bc < 8; ++bc) {
        int b2 = bc & 1, c = bc >> 1;
        int ls = lh * 64 + a2 * 32 + 16 * b2 + 4 * c;
        u32 lo = (u32)Cs[ls * 136 + d] | ((u32)Cs[(ls + 1) * 136 + d] << 16);
        u32 hi = (u32)Cs[(ls + 2) * 136 + d] | ((u32)Cs[(ls + 3) * 136 + d] << 16);
        *(uint2*)(dst + a2 * 32 + 8 * c + 4 * b2) = make_uint2(lo, hi);
      }
    }
  }
}

// ---------------- bf16 GEMM: C(MxN) = A(MxK) @ Bt(NxK)^T, fp32 out ----------------
// 1D grid + bijective XCD swizzle (T1): xcd = id&7 owns (M/128)/8 contiguous
// row-panels (A L2-resident per XCD) x all column-panels; old dim3(16,32)
// mapping made every XCD stream ALL of A through its private L2.
// fp32 epilogue: direct per-lane dword stores (no LDS round-trip, no barriers).
template <int OUT_BF16>
__global__ __launch_bounds__(256, 3) void k_gemm_bt(
    const u16* __restrict__ A, const u16* __restrict__ Bt, void* __restrict__ Cv,
    int M, int N, int K) {
  __shared__ u16 smem2[16384];
  u16* As = smem2;
  u16* Bs = smem2 + 8192;
  const int tid = threadIdx.x;
  const int wave = tid >> 6, lane = tid & 63;
  const int wr = wave >> 1, wc = wave & 1;
  const int quad = lane >> 4, fm = lane & 15;
  // bijective XCD swizzle: requires (M/128) % 8 == 0 (holds: M=4096 -> 32).
  const int id = blockIdx.x;
  const int xcd = id & 7, wq = id >> 3;
  const int byPerXcd = (M >> 7) >> 3;  // 4
  const int by = xcd * byPerXcd + (wq % byPerXcd);
  const int bx = wq / byPerXcd;
  const int m0 = by * 128, n0 = bx * 128;
  f32x4 acc[4][4];
  for (int i = 0; i < 4; ++i)
    for (int j = 0; j < 4; ++j)
      for (int r = 0; r < 4; ++r) acc[i][j][r] = 0.0f;

  const int lrow = lane >> 3;
  const int lcol = (lane & 7) * 8;
  const int fk = quad * 8;

  for (int kt = 0; kt < K; kt += 64) {
    for (int p = 0; p < 4; ++p) {
      int roff = wave * 32 + p * 8 + lrow;
      gl_lds16(A + (size_t)(m0 + roff) * K + kt + lcol,
               As + wave * 2048 + p * 512 + lane * 8);
      gl_lds16(Bt + (size_t)(n0 + roff) * K + kt + lcol,
               Bs + wave * 2048 + p * 512 + lane * 8);
    }
    __syncthreads();
    for (int s = 0; s < 2; ++s) {
      bf16x8 af[4], bfr[4];
      for (int i = 0; i < 4; ++i)
        af[i] = *(const bf16x8*)(As + (wr * 64 + i * 16 + fm) * 64 + s * 32 + fk);
      for (int j = 0; j < 4; ++j)
        bfr[j] = *(const bf16x8*)(Bs + (wc * 64 + j * 16 + fm) * 64 + s * 32 + fk);
      for (int i = 0; i < 4; ++i)
        for (int j = 0; j < 4; ++j)
          acc[i][j] = __builtin_amdgcn_mfma_f32_16x16x32_bf16(af[i], bfr[j],
                                                              acc[i][j], 0, 0, 0);
    }
    __syncthreads();
  }

  if (OUT_BF16) {
    u16* Cs = smem2;
    for (int hh = 0; hh < 2; ++hh) {
      if (hh) __syncthreads();
      if (wr == hh)
        for (int i = 0; i < 4; ++i)
          for (int j = 0; j < 4; ++j)
            for (int r = 0; r < 4; ++r)
              Cs[(i * 16 + quad * 4 + r) * 136 + wc * 64 + j * 16 + fm] =
                  f2bf(acc[i][j][r]);
      __syncthreads();
      for (int it = 0; it < 4; ++it) {
        int row = it * 16 + (tid >> 4);
        int col = (tid & 15) * 8;
        uint4 v = *(const uint4*)(Cs + row * 136 + col);
        *(uint4*)((u16*)Cv + (size_t)(m0 + hh * 64 + row) * N + n0 + col) = v;
      }
    }
  } else {
    float* Cf = (float*)Cv;
#pragma unroll
    for (int i = 0; i < 4; ++i)
#pragma unroll
      for (int j = 0; j < 4; ++j)
#pragma unroll
        for (int r = 0; r < 4; ++r)
          Cf[(size_t)(m0 + wr * 64 + i * 16 + quad * 4 + r) * N + n0 + wc * 64 +
             j * 16 + fm] = acc[i][j][r];
  }
}

// ---------------- flash attention (S^T, no-max softmax, 2 groups/wave, dbuf) ----------------
// 1D 512 blocks; xcd = bid&7 owns exactly one (b,g) K/V set (3MB < 4MB L2).
// (Known-good version: the 512-thread/256-row variant diverged under graph
// replay — reverted per rigor discipline.)
__global__ __launch_bounds__(256, 2) void k_attn(const u16* __restrict__ Qb,
                                                 const u16* __restrict__ Kb,
                                                 const u16* __restrict__ Vtb,
                                                 u16* __restrict__ AO) {
  __shared__ u16 smem3[32768];
  const int tid = threadIdx.x, wave = tid >> 6, lane = tid & 63;
  const int quad = lane >> 4, fm = lane & 15;
  const int f7 = fm & 7;
  const int bid = blockIdx.x;
  const int xcd = bid & 7, w = bid >> 3;
  const int b = xcd >> 2, g = xcd & 3;
  const int h = g * 4 + (w & 3);
  const int qt = w >> 2;
  const int bh = b * 16 + h;
  const u16* Kg = Kb + ((size_t)(b * KV_ + g)) * L_ * D_;
  const u16* Vg = Vtb + ((size_t)(b * KV_ + g)) * D_ * L_;

  const u16* Qg = Qb + ((size_t)bh * L_ + qt * 128 + wave * 32 + fm) * D_;
  bf16x8 qf1[4], qf2[4];
  for (int ks = 0; ks < 4; ++ks) {
    qf1[ks] = *(const bf16x8*)(Qg + ks * 32 + quad * 8);
    qf2[ks] = *(const bf16x8*)(Qg + 16 * D_ + ks * 32 + quad * 8);
  }

  f32x4 o1[8], o2[8];
  for (int f = 0; f < 8; ++f)
    for (int r = 0; r < 4; ++r) { o1[f][r] = 0.0f; o2[f][r] = 0.0f; }
  float lr1 = 0.0f, lr2 = 0.0f;
  const f32x4 fz = {0.0f, 0.0f, 0.0f, 0.0f};

  const int eK = wave * 2048 + (lane << 3);
  const int cK = lane & 15;
  const int cV = lane & 7;

#define STAGE(kt_, buf_)                                                      \
  {                                                                           \
    u16* Kd = smem3 + (buf_)*16384;                                           \
    u16* Vd = smem3 + (buf_)*16384 + 8192;                                    \
    for (int p = 0; p < 4; ++p) {                                             \
      int e = eK + p * 512;                                                   \
      int rowK = e >> 7;                                                      \
      int gK = (cK & 8) | ((cK & 7) ^ (rowK & 7));                            \
      gl_lds16(Kg + (size_t)((kt_)*64 + rowK) * 128 + gK * 8, Kd + e);        \
      int rowV = e >> 6;                                                      \
      int gV = cV ^ (rowV & 7);                                               \
      gl_lds16(Vg + (size_t)rowV * L_ + (kt_)*64 + gV * 8, Vd + e);           \
    }                                                                         \
  }

  STAGE(0, 0);
  for (int kt = 0; kt < 32; ++kt) {
    __syncthreads();
    if (kt + 1 < 32) STAGE(kt + 1, (kt + 1) & 1);
    const u16* Ks = smem3 + (kt & 1) * 16384;
    const u16* Vs = Ks + 8192;

    f32x4 s1[4], s2[4];
    __builtin_amdgcn_s_setprio(1);
    {
      int cp = (quad & 8) | (quad ^ f7);
      for (int n = 0; n < 4; ++n) {
        bf16x8 kf = *(const bf16x8*)(Ks + (n * 16 + fm) * 128 + cp * 8);
        s1[n] = __builtin_amdgcn_mfma_f32_16x16x32_bf16(kf, qf1[0], fz, 0, 0, 0);
        s2[n] = __builtin_amdgcn_mfma_f32_16x16x32_bf16(kf, qf2[0], fz, 0, 0, 0);
      }
    }
    for (int ks = 1; ks < 4; ++ks) {
      int c = 4 * ks + quad;
      int cp = (c & 8) | ((c & 7) ^ f7);
      for (int n = 0; n < 4; ++n) {
        bf16x8 kf = *(const bf16x8*)(Ks + (n * 16 + fm) * 128 + cp * 8);
        s1[n] = __builtin_amdgcn_mfma_f32_16x16x32_bf16(kf, qf1[ks], s1[n], 0, 0, 0);
        s2[n] = __builtin_amdgcn_mfma_f32_16x16x32_bf16(kf, qf2[ks], s2[n], 0, 0, 0);
      }
    }
    __builtin_amdgcn_s_setprio(0);

    u32 pk1[4][2], pk2[4][2];
    float rs1 = 0.0f, rs2 = 0.0f;
    for (int n = 0; n < 4; ++n) {
      float a0 = __builtin_amdgcn_exp2f(s1[n][0]);
      float a1 = __builtin_amdgcn_exp2f(s1[n][1]);
      float a2 = __builtin_amdgcn_exp2f(s1[n][2]);
      float a3 = __builtin_amdgcn_exp2f(s1[n][3]);
      rs1 += (a0 + a1) + (a2 + a3);
      pk1[n][0] = pkbf(a0, a1);
      pk1[n][1] = pkbf(a2, a3);
      float b0 = __builtin_amdgcn_exp2f(s2[n][0]);
      float b1 = __builtin_amdgcn_exp2f(s2[n][1]);
      float b2 = __builtin_amdgcn_exp2f(s2[n][2]);
      float b3 = __builtin_amdgcn_exp2f(s2[n][3]);
      rs2 += (b0 + b1) + (b2 + b3);
      pk2[n][0] = pkbf(b0, b1);
      pk2[n][1] = pkbf(b2, b3);
    }
    lr1 += rs1;
    lr2 += rs2;

    __builtin_amdgcn_s_setprio(1);
    for (int ks2 = 0; ks2 < 2; ++ks2) {
      union { u32 u[4]; bf16x8 v; } pa1, pa2;
      pa1.u[0] = pk1[2 * ks2][0];
      pa1.u[1] = pk1[2 * ks2][1];
      pa1.u[2] = pk1[2 * ks2 + 1][0];
      pa1.u[3] = pk1[2 * ks2 + 1][1];
      pa2.u[0] = pk2[2 * ks2][0];
      pa2.u[1] = pk2[2 * ks2][1];
      pa2.u[2] = pk2[2 * ks2 + 1][0];
      pa2.u[3] = pk2[2 * ks2 + 1][1];
      int chunk = (4 * ks2 + quad) ^ f7;
      for (int f = 0; f < 8; ++f) {
        bf16x8 vv = *(const bf16x8*)(Vs + (f * 16 + fm) * 64 + chunk * 8);
        o1[f] = __builtin_amdgcn_mfma_f32_16x16x32_bf16(pa1.v, vv, o1[f], 0, 0, 0);
        o2[f] = __builtin_amdgcn_mfma_f32_16x16x32_bf16(pa2.v, vv, o2[f], 0, 0, 0);
      }
    }
    __builtin_amdgcn_s_setprio(0);
  }
#undef STAGE

  const size_t tok0 = (size_t)b * L_ + qt * 128;
  for (int grp = 0; grp < 2; ++grp) {
    f32x4* o = grp ? o2 : o1;
    float lr = grp ? lr2 : lr1;
    lr += __shfl_xor(lr, 16);
    lr += __shfl_xor(lr, 32);
    float li = 1.0f / lr;
    float l0 = __shfl(li, (lane & 48) | (quad * 4 + 0));
    float l1 = __shfl(li, (lane & 48) | (quad * 4 + 1));
    float l2 = __shfl(li, (lane & 48) | (quad * 4 + 2));
    float l3 = __shfl(li, (lane & 48) | (quad * 4 + 3));
    __syncthreads();
    for (int f = 0; f < 8; ++f) {
      int e = (wave * 16 + quad * 4) * 136 + f * 16 + fm;
      smem3[e] = f2bf(o[f][0] * l0);
      smem3[e + 136] = f2bf(o[f][1] * l1);
      smem3[e + 272] = f2bf(o[f][2] * l2);
      smem3[e + 408] = f2bf(o[f][3] * l3);
    }
    __syncthreads();
    for (int it = 0; it < 8; ++it) {
      int crow = (tid >> 6) * 16 + it * 2 + (lane >> 5);
      int q = (crow >> 4) * 32 + grp * 16 + (crow & 15);
      int cc = (lane & 31) * 4;
      uint2 v = *(const uint2*)(smem3 + crow * 136 + cc);
      *(uint2*)(AO + (tok0 + q) * (H_ * D_) + h * D_ + cc) = v;
    }
  }
}

// ---------------- launcher ----------------
extern "C" void kernel_launch(void* const* d_in, const int* in_sizes, int n_in,
                              void* d_out, int out_size, void* d_ws,
                              size_t ws_size, hipStream_t stream) {
  const float* hidden = (const float*)d_in[0];
  const float* cosp = (const float*)d_in[1];
  const float* sinp = (const float*)d_in[2];
  const float* Wq = (const float*)d_in[3];
  const float* Wk = (const float*)d_in[4];
  const float* Wv = (const float*)d_in[5];
  const float* Wo = (const float*)d_in[6];
  const float* qw = (const float*)d_in[7];
  const float* kw = (const float*)d_in[8];
  float* out = (float*)d_out;

  char* w = (char*)d_ws;
  u16* Xb = (u16*)(w);                          // 4096x2048 bf16, 16MB
  u16* Wtqkv = (u16*)(w + (16u << 20));         // 3072x2048 bf16, 12MB
  u16* Wto = (u16*)(w + (28u << 20));           // 2048x2048 bf16, 8MB
  u16* Qb = (u16*)(w + (36u << 20));            // 16MB
  u16* Kb = (u16*)(w + (52u << 20));            // 4MB
  u16* Vtb = (u16*)(w + (56u << 20));           // 4MB (ends 60MB)
  u16* AO = Xb;                                 // reuse after gemm_qkv

  k_prep<<<14336, 256, 0, stream>>>(hidden, Xb, Wq, Wk, Wv, Wtqkv);
  k_gemm_qkv<<<dim3(704), dim3(512), 131072, stream>>>(Xb, Wtqkv, cosp, sinp,
                                                       qw, kw, Qb, Kb, Vtb,
                                                       Wo, Wto);
  k_attn<<<dim3(512), 256, 0, stream>>>(Qb, Kb, Vtb, AO);
  k_gemm_bt<0><<<dim3(512), 256, 0, stream>>>(AO, Wto, out, 4096, 2048, 2048);
}